// Round 1
// baseline (1064.297 us; speedup 1.0000x reference)
//
#include <hip/hip_runtime.h>
#include <math.h>

// Problem constants (B,N,F_IN,HID,OUT,H,D) = (32,512,256,512,512,4,128)
#define BATCH 32
#define NNODE 512
#define FIN   256
#define HIDC  512
#define OUTC  512
#define NHEAD 4
#define HDIM  128
#define EPSV  1e-5f
#define ALPHA_LR 0.2f

// ---------------------------------------------------------------------------
// Shared 128x128-tile fp32 microkernel: 256 threads, 8x8 accum per thread.
// LDS layout As[kk][row] / Bs[kk][col], leading dim 132 (pad 4 -> 2-way max
// bank aliasing on stores, float4-aligned reads).
// ---------------------------------------------------------------------------
__device__ __forceinline__ void tile_compute_128(const float As[16][132],
                                                 const float Bs[16][132],
                                                 float acc[8][8], int tx, int ty) {
#pragma unroll
  for (int kk = 0; kk < 16; ++kk) {
    float4 a0 = *(const float4*)&As[kk][ty * 8];
    float4 a1 = *(const float4*)&As[kk][ty * 8 + 4];
    float4 b0 = *(const float4*)&Bs[kk][tx * 8];
    float4 b1 = *(const float4*)&Bs[kk][tx * 8 + 4];
    float a[8] = {a0.x, a0.y, a0.z, a0.w, a1.x, a1.y, a1.z, a1.w};
    float b[8] = {b0.x, b0.y, b0.z, b0.w, b1.x, b1.y, b1.z, b1.w};
#pragma unroll
    for (int i = 0; i < 8; ++i)
#pragma unroll
      for (int j = 0; j < 8; ++j) acc[i][j] = fmaf(a[i], b[j], acc[i][j]);
  }
}

// ---------------------------------------------------------------------------
// K1: support = x @ gc_w      [16384,256]@[256,512] -> R0
// ---------------------------------------------------------------------------
__global__ __launch_bounds__(256) void k_support(const float* __restrict__ X,
                                                 const float* __restrict__ W,
                                                 float* __restrict__ S) {
  __shared__ float As[16][132], Bs[16][132];
  const int t = threadIdx.x, tx = t & 15, ty = t >> 4;
  const int rowBase = blockIdx.y * 128, colBase = blockIdx.x * 128;
  float acc[8][8] = {};
  for (int k0 = 0; k0 < FIN; k0 += 16) {
#pragma unroll
    for (int l = 0; l < 2; ++l) {
      int fid = t + l * 256;
      int r = fid >> 2, kq = (fid & 3) * 4;
      float4 va = *(const float4*)&X[(size_t)(rowBase + r) * FIN + k0 + kq];
      As[kq + 0][r] = va.x; As[kq + 1][r] = va.y; As[kq + 2][r] = va.z; As[kq + 3][r] = va.w;
      int kk = fid >> 5, c4 = (fid & 31) * 4;
      *(float4*)&Bs[kk][c4] = *(const float4*)&W[(size_t)(k0 + kk) * HIDC + colBase + c4];
    }
    __syncthreads();
    tile_compute_128(As, Bs, acc, tx, ty);
    __syncthreads();
  }
#pragma unroll
  for (int i = 0; i < 8; ++i) {
    float* dst = &S[(size_t)(rowBase + ty * 8 + i) * HIDC + colBase + tx * 8];
    *(float4*)dst = make_float4(acc[i][0], acc[i][1], acc[i][2], acc[i][3]);
    *(float4*)(dst + 4) = make_float4(acc[i][4], acc[i][5], acc[i][6], acc[i][7]);
  }
}

// ---------------------------------------------------------------------------
// K2: g = relu(bn1(adj @ support_b + gc_b))   per batch -> R1
// ---------------------------------------------------------------------------
__global__ __launch_bounds__(256) void k_gcn(const float* __restrict__ ADJ,
                                             const float* __restrict__ S,
                                             float* __restrict__ G,
                                             const float* __restrict__ gcb,
                                             const float* __restrict__ g1,
                                             const float* __restrict__ b1,
                                             const float* __restrict__ m1,
                                             const float* __restrict__ v1) {
  __shared__ float As[16][132], Bs[16][132];
  const int t = threadIdx.x, tx = t & 15, ty = t >> 4;
  const int rowBase = blockIdx.y * 128, colBase = blockIdx.x * 128;
  const int b = blockIdx.z;
  const float* Sb = S + (size_t)b * NNODE * HIDC;
  float acc[8][8] = {};
  for (int k0 = 0; k0 < NNODE; k0 += 16) {
#pragma unroll
    for (int l = 0; l < 2; ++l) {
      int fid = t + l * 256;
      int r = fid >> 2, kq = (fid & 3) * 4;
      float4 va = *(const float4*)&ADJ[(size_t)(rowBase + r) * NNODE + k0 + kq];
      As[kq + 0][r] = va.x; As[kq + 1][r] = va.y; As[kq + 2][r] = va.z; As[kq + 3][r] = va.w;
      int kk = fid >> 5, c4 = (fid & 31) * 4;
      *(float4*)&Bs[kk][c4] = *(const float4*)&Sb[(size_t)(k0 + kk) * HIDC + colBase + c4];
    }
    __syncthreads();
    tile_compute_128(As, Bs, acc, tx, ty);
    __syncthreads();
  }
  float sc[8], of[8];
#pragma unroll
  for (int j = 0; j < 8; ++j) {
    int c = colBase + tx * 8 + j;
    float s = g1[c] * rsqrtf(v1[c] + EPSV);
    sc[j] = s;
    of[j] = (gcb[c] - m1[c]) * s + b1[c];
  }
  float* Gb = G + (size_t)b * NNODE * HIDC;
#pragma unroll
  for (int i = 0; i < 8; ++i) {
    float vo[8];
#pragma unroll
    for (int j = 0; j < 8; ++j) vo[j] = fmaxf(fmaf(acc[i][j], sc[j], of[j]), 0.0f);
    float* dst = &Gb[(size_t)(rowBase + ty * 8 + i) * HIDC + colBase + tx * 8];
    *(float4*)dst = make_float4(vo[0], vo[1], vo[2], vo[3]);
    *(float4*)(dst + 4) = make_float4(vo[4], vo[5], vo[6], vo[7]);
  }
}

// ---------------------------------------------------------------------------
// K3: hh = g @ gat_w^T   [16384,512]@[512,512]^T -> R0  (col j = h*128+d)
// ---------------------------------------------------------------------------
__global__ __launch_bounds__(256) void k_hh(const float* __restrict__ G,
                                            const float* __restrict__ WT,
                                            float* __restrict__ HH) {
  __shared__ float As[16][132], Bs[16][132];
  const int t = threadIdx.x, tx = t & 15, ty = t >> 4;
  const int rowBase = blockIdx.y * 128, colBase = blockIdx.x * 128;
  float acc[8][8] = {};
  for (int k0 = 0; k0 < HIDC; k0 += 16) {
#pragma unroll
    for (int l = 0; l < 2; ++l) {
      int fid = t + l * 256;
      int r = fid >> 2, kq = (fid & 3) * 4;
      float4 va = *(const float4*)&G[(size_t)(rowBase + r) * HIDC + k0 + kq];
      As[kq + 0][r] = va.x; As[kq + 1][r] = va.y; As[kq + 2][r] = va.z; As[kq + 3][r] = va.w;
      float4 vb = *(const float4*)&WT[(size_t)(colBase + r) * HIDC + k0 + kq];
      Bs[kq + 0][r] = vb.x; Bs[kq + 1][r] = vb.y; Bs[kq + 2][r] = vb.z; Bs[kq + 3][r] = vb.w;
    }
    __syncthreads();
    tile_compute_128(As, Bs, acc, tx, ty);
    __syncthreads();
  }
#pragma unroll
  for (int i = 0; i < 8; ++i) {
    float* dst = &HH[(size_t)(rowBase + ty * 8 + i) * OUTC + colBase + tx * 8];
    *(float4*)dst = make_float4(acc[i][0], acc[i][1], acc[i][2], acc[i][3]);
    *(float4*)(dst + 4) = make_float4(acc[i][4], acc[i][5], acc[i][6], acc[i][7]);
  }
}

// ---------------------------------------------------------------------------
// K4: e = leakyrelu(hh_bh @ hh_bh^T)  per (bb,h) of an 8-batch chunk -> R1
// ---------------------------------------------------------------------------
__global__ __launch_bounds__(256) void k_e(const float* __restrict__ HH,
                                           float* __restrict__ E, int b0) {
  __shared__ float As[16][132], Bs[16][132];
  const int t = threadIdx.x, tx = t & 15, ty = t >> 4;
  const int rowBase = blockIdx.y * 128, colBase = blockIdx.x * 128;
  const int bb = blockIdx.z >> 2, h = blockIdx.z & 3;
  const float* hb = HH + (size_t)(b0 + bb) * NNODE * OUTC + h * HDIM;
  float acc[8][8] = {};
  for (int k0 = 0; k0 < HDIM; k0 += 16) {
#pragma unroll
    for (int l = 0; l < 2; ++l) {
      int fid = t + l * 256;
      int r = fid >> 2, kq = (fid & 3) * 4;
      float4 va = *(const float4*)&hb[(size_t)(rowBase + r) * OUTC + k0 + kq];
      As[kq + 0][r] = va.x; As[kq + 1][r] = va.y; As[kq + 2][r] = va.z; As[kq + 3][r] = va.w;
      float4 vb = *(const float4*)&hb[(size_t)(colBase + r) * OUTC + k0 + kq];
      Bs[kq + 0][r] = vb.x; Bs[kq + 1][r] = vb.y; Bs[kq + 2][r] = vb.z; Bs[kq + 3][r] = vb.w;
    }
    __syncthreads();
    tile_compute_128(As, Bs, acc, tx, ty);
    __syncthreads();
  }
  float* Eb = E + (size_t)(bb * NHEAD + h) * NNODE * NNODE;
#pragma unroll
  for (int i = 0; i < 8; ++i) {
    float vo[8];
#pragma unroll
    for (int j = 0; j < 8; ++j) {
      float e = acc[i][j];
      vo[j] = e > 0.0f ? e : ALPHA_LR * e;
    }
    float* dst = &Eb[(size_t)(rowBase + ty * 8 + i) * NNODE + colBase + tx * 8];
    *(float4*)dst = make_float4(vo[0], vo[1], vo[2], vo[3]);
    *(float4*)(dst + 4) = make_float4(vo[4], vo[5], vo[6], vo[7]);
  }
}

// ---------------------------------------------------------------------------
// K5: row softmax over 512 cols, in-place. One wave (64 lanes) per row,
// 8 elements per lane; shuffle-reduce max & sum.
// ---------------------------------------------------------------------------
__global__ __launch_bounds__(256) void k_softmax(float* __restrict__ E) {
  const int wave = threadIdx.x >> 6, lane = threadIdx.x & 63;
  float* p = E + ((size_t)blockIdx.x * 4 + wave) * NNODE + lane * 8;
  float4 v0 = *(float4*)p;
  float4 v1 = *(float4*)(p + 4);
  float mx = fmaxf(fmaxf(fmaxf(v0.x, v0.y), fmaxf(v0.z, v0.w)),
                   fmaxf(fmaxf(v1.x, v1.y), fmaxf(v1.z, v1.w)));
#pragma unroll
  for (int o = 32; o; o >>= 1) mx = fmaxf(mx, __shfl_xor(mx, o));
  v0.x = __expf(v0.x - mx); v0.y = __expf(v0.y - mx);
  v0.z = __expf(v0.z - mx); v0.w = __expf(v0.w - mx);
  v1.x = __expf(v1.x - mx); v1.y = __expf(v1.y - mx);
  v1.z = __expf(v1.z - mx); v1.w = __expf(v1.w - mx);
  float s = v0.x + v0.y + v0.z + v0.w + v1.x + v1.y + v1.z + v1.w;
#pragma unroll
  for (int o = 32; o; o >>= 1) s += __shfl_xor(s, o);
  const float inv = 1.0f / s;
  v0.x *= inv; v0.y *= inv; v0.z *= inv; v0.w *= inv;
  v1.x *= inv; v1.y *= inv; v1.z *= inv; v1.w *= inv;
  *(float4*)p = v0;
  *(float4*)(p + 4) = v1;
}

// ---------------------------------------------------------------------------
// K6: o = att @ hh_bh  [512,512]@[512,128] per (bb,h) -> R2 slice.
// 64x64 tile / 4x4 per thread (thin N=128 -> more blocks).
// ---------------------------------------------------------------------------
__global__ __launch_bounds__(256) void k_o(const float* __restrict__ E,
                                           const float* __restrict__ HH,
                                           float* __restrict__ O, int b0) {
  __shared__ float As[16][68], Bs[16][68];
  const int t = threadIdx.x, tx = t & 15, ty = t >> 4;
  const int rowBase = blockIdx.y * 64, colBase = blockIdx.x * 64;
  const int bb = blockIdx.z >> 2, h = blockIdx.z & 3;
  const float* Pb = E + (size_t)(bb * NHEAD + h) * NNODE * NNODE;
  const float* hb = HH + (size_t)(b0 + bb) * NNODE * OUTC + h * HDIM;
  float acc[4][4] = {};
  for (int k0 = 0; k0 < NNODE; k0 += 16) {
    {
      int r = t >> 2, kq = (t & 3) * 4;
      float4 va = *(const float4*)&Pb[(size_t)(rowBase + r) * NNODE + k0 + kq];
      As[kq + 0][r] = va.x; As[kq + 1][r] = va.y; As[kq + 2][r] = va.z; As[kq + 3][r] = va.w;
      int kk = t >> 4, c4 = (t & 15) * 4;
      *(float4*)&Bs[kk][c4] = *(const float4*)&hb[(size_t)(k0 + kk) * OUTC + colBase + c4];
    }
    __syncthreads();
#pragma unroll
    for (int kk = 0; kk < 16; ++kk) {
      float4 a4 = *(const float4*)&As[kk][ty * 4];
      float4 b4 = *(const float4*)&Bs[kk][tx * 4];
      float a[4] = {a4.x, a4.y, a4.z, a4.w};
      float b[4] = {b4.x, b4.y, b4.z, b4.w};
#pragma unroll
      for (int i = 0; i < 4; ++i)
#pragma unroll
        for (int j = 0; j < 4; ++j) acc[i][j] = fmaf(a[i], b[j], acc[i][j]);
    }
    __syncthreads();
  }
  float* Ob = O + (size_t)(b0 + bb) * NNODE * OUTC + h * HDIM;
#pragma unroll
  for (int i = 0; i < 4; ++i)
    *(float4*)&Ob[(size_t)(rowBase + ty * 4 + i) * OUTC + colBase + tx * 4] =
        make_float4(acc[i][0], acc[i][1], acc[i][2], acc[i][3]);
}

// ---------------------------------------------------------------------------
// K7: y = relu(bn2(conv1d(o) + conv_b)), written as [B,N,OUT].
// conv1d(k=3,pad=1) over node axis == GEMM with K = 3*512 (k-major),
// A rows shifted by (k-1) with zero pad at batch edges.
// ---------------------------------------------------------------------------
__global__ __launch_bounds__(256) void k_conv(const float* __restrict__ O,
                                              const float* __restrict__ CW,
                                              const float* __restrict__ cb,
                                              const float* __restrict__ g2,
                                              const float* __restrict__ b2,
                                              const float* __restrict__ m2,
                                              const float* __restrict__ v2,
                                              float* __restrict__ Y) {
  __shared__ float As[16][132], Bs[16][132];
  const int t = threadIdx.x, tx = t & 15, ty = t >> 4;
  const int rowBase = blockIdx.y * 128, colBase = blockIdx.x * 128;
  float acc[8][8] = {};
  for (int k0 = 0; k0 < 3 * OUTC; k0 += 16) {
    const int ktap = k0 >> 9;     // 0..2 (constant within a 16-wide K tile)
    const int cib  = k0 & 511;
#pragma unroll
    for (int l = 0; l < 2; ++l) {
      int fid = t + l * 256;
      int r = fid >> 2, kq = (fid & 3) * 4;
      int row = rowBase + r;
      int b = row >> 9, n = row & 511;
      int sn = n + ktap - 1;
      float4 va = make_float4(0.f, 0.f, 0.f, 0.f);
      if ((unsigned)sn < (unsigned)NNODE)
        va = *(const float4*)&O[((size_t)(b << 9) + sn) * OUTC + cib + kq];
      As[kq + 0][r] = va.x; As[kq + 1][r] = va.y; As[kq + 2][r] = va.z; As[kq + 3][r] = va.w;
      int c = fid >> 2;  // output-channel index within tile (B^T load)
#pragma unroll
      for (int q = 0; q < 4; ++q)
        Bs[kq + q][c] = CW[(size_t)(colBase + c) * (OUTC * 3) + (size_t)(cib + kq + q) * 3 + ktap];
    }
    __syncthreads();
    tile_compute_128(As, Bs, acc, tx, ty);
    __syncthreads();
  }
  float sc[8], of[8];
#pragma unroll
  for (int j = 0; j < 8; ++j) {
    int c = colBase + tx * 8 + j;
    float s = g2[c] * rsqrtf(v2[c] + EPSV);
    sc[j] = s;
    of[j] = (cb[c] - m2[c]) * s + b2[c];
  }
#pragma unroll
  for (int i = 0; i < 8; ++i) {
    float vo[8];
#pragma unroll
    for (int j = 0; j < 8; ++j) vo[j] = fmaxf(fmaf(acc[i][j], sc[j], of[j]), 0.0f);
    float* dst = &Y[(size_t)(rowBase + ty * 8 + i) * OUTC + colBase + tx * 8];
    *(float4*)dst = make_float4(vo[0], vo[1], vo[2], vo[3]);
    *(float4*)(dst + 4) = make_float4(vo[4], vo[5], vo[6], vo[7]);
  }
}

// ---------------------------------------------------------------------------
extern "C" void kernel_launch(void* const* d_in, const int* in_sizes, int n_in,
                              void* d_out, int out_size, void* d_ws, size_t ws_size,
                              hipStream_t stream) {
  const float* x     = (const float*)d_in[0];
  const float* adj   = (const float*)d_in[1];
  const float* gc_w  = (const float*)d_in[2];
  const float* gc_b  = (const float*)d_in[3];
  const float* bn1_g = (const float*)d_in[4];
  const float* bn1_b = (const float*)d_in[5];
  const float* bn1_m = (const float*)d_in[6];
  const float* bn1_v = (const float*)d_in[7];
  const float* gat_w = (const float*)d_in[8];
  const float* conv_w= (const float*)d_in[9];
  const float* conv_b= (const float*)d_in[10];
  const float* bn2_g = (const float*)d_in[11];
  const float* bn2_b = (const float*)d_in[12];
  const float* bn2_m = (const float*)d_in[13];
  const float* bn2_v = (const float*)d_in[14];
  float* out = (float*)d_out;

  // Workspace plan (needs 96 MB + 32 MB = fits in 100,663,296 B):
  //   R0 [33.5MB]: support, then hh   (support dead after K2)
  //   R1 [33.5MB]: g, then e-chunks   (g dead after K3)
  //   R2 [33.5MB]: o (full, for conv)
  char* ws = (char*)d_ws;
  float* R0 = (float*)(ws);
  float* R1 = (float*)(ws + (size_t)33554432);
  float* R2 = (float*)(ws + (size_t)67108864);

  // K1: support = x @ gc_w -> R0
  k_support<<<dim3(4, 128), 256, 0, stream>>>(x, gc_w, R0);
  // K2: g = relu(bn1(adj @ support + gc_b)) -> R1
  k_gcn<<<dim3(4, 4, BATCH), 256, 0, stream>>>(adj, R0, R1, gc_b, bn1_g, bn1_b, bn1_m, bn1_v);
  // K3: hh = g @ gat_w^T -> R0
  k_hh<<<dim3(4, 128), 256, 0, stream>>>(R1, gat_w, R0);
  // K4-6: attention in 4 chunks of 8 batches (e-chunk lives in R1)
  for (int c = 0; c < 4; ++c) {
    int b0 = c * 8;
    k_e<<<dim3(4, 4, 32), 256, 0, stream>>>(R0, R1, b0);
    k_softmax<<<dim3(4096), 256, 0, stream>>>(R1);
    k_o<<<dim3(2, 8, 32), 256, 0, stream>>>(R1, R0, R2, b0);
  }
  // K7: conv1d + bn2 + relu -> out [B,N,OUT]
  k_conv<<<dim3(4, 128), 256, 0, stream>>>(R2, conv_w, conv_b, bn2_g, bn2_b, bn2_m, bn2_v, out);
}

// Round 2
// 745.769 us; speedup vs baseline: 1.4271x; 1.4271x over previous
//
#include <hip/hip_runtime.h>
#include <math.h>

// Problem constants (B,N,F_IN,HID,OUT,H,D) = (32,512,256,512,512,4,128)
#define BATCH 32
#define NNODE 512
#define FIN   256
#define HIDC  512
#define OUTC  512
#define NHEAD 4
#define HDIM  128
#define EPSV  1e-5f
#define ALPHA_LR 0.2f

typedef _Float16 half8 __attribute__((ext_vector_type(8)));
typedef float floatx4 __attribute__((ext_vector_type(4)));

#define GLOBAL_TO_LDS16(g, l)                                                  \
  __builtin_amdgcn_global_load_lds(                                            \
      (const __attribute__((address_space(1))) void*)(g),                      \
      (__attribute__((address_space(3))) void*)(l), 16, 0, 0)

// ---------------------------------------------------------------------------
// Shared 128x128-tile fp32 microkernel: 256 threads, 8x8 accum per thread.
// ---------------------------------------------------------------------------
__device__ __forceinline__ void tile_compute_128(const float As[16][132],
                                                 const float Bs[16][132],
                                                 float acc[8][8], int tx, int ty) {
#pragma unroll
  for (int kk = 0; kk < 16; ++kk) {
    float4 a0 = *(const float4*)&As[kk][ty * 8];
    float4 a1 = *(const float4*)&As[kk][ty * 8 + 4];
    float4 b0 = *(const float4*)&Bs[kk][tx * 8];
    float4 b1 = *(const float4*)&Bs[kk][tx * 8 + 4];
    float a[8] = {a0.x, a0.y, a0.z, a0.w, a1.x, a1.y, a1.z, a1.w};
    float b[8] = {b0.x, b0.y, b0.z, b0.w, b1.x, b1.y, b1.z, b1.w};
#pragma unroll
    for (int i = 0; i < 8; ++i)
#pragma unroll
      for (int j = 0; j < 8; ++j) acc[i][j] = fmaf(a[i], b[j], acc[i][j]);
  }
}

// ---------------------------------------------------------------------------
// K1: support = x @ gc_w      [16384,256]@[256,512] -> R0
// ---------------------------------------------------------------------------
__global__ __launch_bounds__(256) void k_support(const float* __restrict__ X,
                                                 const float* __restrict__ W,
                                                 float* __restrict__ S) {
  __shared__ float As[16][132], Bs[16][132];
  const int t = threadIdx.x, tx = t & 15, ty = t >> 4;
  const int rowBase = blockIdx.y * 128, colBase = blockIdx.x * 128;
  float acc[8][8] = {};
  for (int k0 = 0; k0 < FIN; k0 += 16) {
#pragma unroll
    for (int l = 0; l < 2; ++l) {
      int fid = t + l * 256;
      int r = fid >> 2, kq = (fid & 3) * 4;
      float4 va = *(const float4*)&X[(size_t)(rowBase + r) * FIN + k0 + kq];
      As[kq + 0][r] = va.x; As[kq + 1][r] = va.y; As[kq + 2][r] = va.z; As[kq + 3][r] = va.w;
      int kk = fid >> 5, c4 = (fid & 31) * 4;
      *(float4*)&Bs[kk][c4] = *(const float4*)&W[(size_t)(k0 + kk) * HIDC + colBase + c4];
    }
    __syncthreads();
    tile_compute_128(As, Bs, acc, tx, ty);
    __syncthreads();
  }
#pragma unroll
  for (int i = 0; i < 8; ++i) {
    float* dst = &S[(size_t)(rowBase + ty * 8 + i) * HIDC + colBase + tx * 8];
    *(float4*)dst = make_float4(acc[i][0], acc[i][1], acc[i][2], acc[i][3]);
    *(float4*)(dst + 4) = make_float4(acc[i][4], acc[i][5], acc[i][6], acc[i][7]);
  }
}

// ---------------------------------------------------------------------------
// K2: g = relu(bn1(adj @ support_b + gc_b))   per batch -> R1
// ---------------------------------------------------------------------------
__global__ __launch_bounds__(256) void k_gcn(const float* __restrict__ ADJ,
                                             const float* __restrict__ S,
                                             float* __restrict__ G,
                                             const float* __restrict__ gcb,
                                             const float* __restrict__ g1,
                                             const float* __restrict__ b1,
                                             const float* __restrict__ m1,
                                             const float* __restrict__ v1) {
  __shared__ float As[16][132], Bs[16][132];
  const int t = threadIdx.x, tx = t & 15, ty = t >> 4;
  const int rowBase = blockIdx.y * 128, colBase = blockIdx.x * 128;
  const int b = blockIdx.z;
  const float* Sb = S + (size_t)b * NNODE * HIDC;
  float acc[8][8] = {};
  for (int k0 = 0; k0 < NNODE; k0 += 16) {
#pragma unroll
    for (int l = 0; l < 2; ++l) {
      int fid = t + l * 256;
      int r = fid >> 2, kq = (fid & 3) * 4;
      float4 va = *(const float4*)&ADJ[(size_t)(rowBase + r) * NNODE + k0 + kq];
      As[kq + 0][r] = va.x; As[kq + 1][r] = va.y; As[kq + 2][r] = va.z; As[kq + 3][r] = va.w;
      int kk = fid >> 5, c4 = (fid & 31) * 4;
      *(float4*)&Bs[kk][c4] = *(const float4*)&Sb[(size_t)(k0 + kk) * HIDC + colBase + c4];
    }
    __syncthreads();
    tile_compute_128(As, Bs, acc, tx, ty);
    __syncthreads();
  }
  float sc[8], of[8];
#pragma unroll
  for (int j = 0; j < 8; ++j) {
    int c = colBase + tx * 8 + j;
    float s = g1[c] * rsqrtf(v1[c] + EPSV);
    sc[j] = s;
    of[j] = (gcb[c] - m1[c]) * s + b1[c];
  }
  float* Gb = G + (size_t)b * NNODE * HIDC;
#pragma unroll
  for (int i = 0; i < 8; ++i) {
    float vo[8];
#pragma unroll
    for (int j = 0; j < 8; ++j) vo[j] = fmaxf(fmaf(acc[i][j], sc[j], of[j]), 0.0f);
    float* dst = &Gb[(size_t)(rowBase + ty * 8 + i) * HIDC + colBase + tx * 8];
    *(float4*)dst = make_float4(vo[0], vo[1], vo[2], vo[3]);
    *(float4*)(dst + 4) = make_float4(vo[4], vo[5], vo[6], vo[7]);
  }
}

// ---------------------------------------------------------------------------
// K3: hh = g @ gat_w^T   [16384,512]@[512,512]^T -> R0  (col j = h*128+d)
// ---------------------------------------------------------------------------
__global__ __launch_bounds__(256) void k_hh(const float* __restrict__ G,
                                            const float* __restrict__ WT,
                                            float* __restrict__ HH) {
  __shared__ float As[16][132], Bs[16][132];
  const int t = threadIdx.x, tx = t & 15, ty = t >> 4;
  const int rowBase = blockIdx.y * 128, colBase = blockIdx.x * 128;
  float acc[8][8] = {};
  for (int k0 = 0; k0 < HIDC; k0 += 16) {
#pragma unroll
    for (int l = 0; l < 2; ++l) {
      int fid = t + l * 256;
      int r = fid >> 2, kq = (fid & 3) * 4;
      float4 va = *(const float4*)&G[(size_t)(rowBase + r) * HIDC + k0 + kq];
      As[kq + 0][r] = va.x; As[kq + 1][r] = va.y; As[kq + 2][r] = va.z; As[kq + 3][r] = va.w;
      float4 vb = *(const float4*)&WT[(size_t)(colBase + r) * HIDC + k0 + kq];
      Bs[kq + 0][r] = vb.x; Bs[kq + 1][r] = vb.y; Bs[kq + 2][r] = vb.z; Bs[kq + 3][r] = vb.w;
    }
    __syncthreads();
    tile_compute_128(As, Bs, acc, tx, ty);
    __syncthreads();
  }
#pragma unroll
  for (int i = 0; i < 8; ++i) {
    float* dst = &HH[(size_t)(rowBase + ty * 8 + i) * OUTC + colBase + tx * 8];
    *(float4*)dst = make_float4(acc[i][0], acc[i][1], acc[i][2], acc[i][3]);
    *(float4*)(dst + 4) = make_float4(acc[i][4], acc[i][5], acc[i][6], acc[i][7]);
  }
}

// ---------------------------------------------------------------------------
// K4: e = leakyrelu(hh_bh @ hh_bh^T)  per (bb,h) of an 8-batch chunk -> R1
// ---------------------------------------------------------------------------
__global__ __launch_bounds__(256) void k_e(const float* __restrict__ HH,
                                           float* __restrict__ E, int b0) {
  __shared__ float As[16][132], Bs[16][132];
  const int t = threadIdx.x, tx = t & 15, ty = t >> 4;
  const int rowBase = blockIdx.y * 128, colBase = blockIdx.x * 128;
  const int bb = blockIdx.z >> 2, h = blockIdx.z & 3;
  const float* hb = HH + (size_t)(b0 + bb) * NNODE * OUTC + h * HDIM;
  float acc[8][8] = {};
  for (int k0 = 0; k0 < HDIM; k0 += 16) {
#pragma unroll
    for (int l = 0; l < 2; ++l) {
      int fid = t + l * 256;
      int r = fid >> 2, kq = (fid & 3) * 4;
      float4 va = *(const float4*)&hb[(size_t)(rowBase + r) * OUTC + k0 + kq];
      As[kq + 0][r] = va.x; As[kq + 1][r] = va.y; As[kq + 2][r] = va.z; As[kq + 3][r] = va.w;
      float4 vb = *(const float4*)&hb[(size_t)(colBase + r) * OUTC + k0 + kq];
      Bs[kq + 0][r] = vb.x; Bs[kq + 1][r] = vb.y; Bs[kq + 2][r] = vb.z; Bs[kq + 3][r] = vb.w;
    }
    __syncthreads();
    tile_compute_128(As, Bs, acc, tx, ty);
    __syncthreads();
  }
  float* Eb = E + (size_t)(bb * NHEAD + h) * NNODE * NNODE;
#pragma unroll
  for (int i = 0; i < 8; ++i) {
    float vo[8];
#pragma unroll
    for (int j = 0; j < 8; ++j) {
      float e = acc[i][j];
      vo[j] = e > 0.0f ? e : ALPHA_LR * e;
    }
    float* dst = &Eb[(size_t)(rowBase + ty * 8 + i) * NNODE + colBase + tx * 8];
    *(float4*)dst = make_float4(vo[0], vo[1], vo[2], vo[3]);
    *(float4*)(dst + 4) = make_float4(vo[4], vo[5], vo[6], vo[7]);
  }
}

// ---------------------------------------------------------------------------
// K5: row softmax over 512 cols, in-place. One wave per row.
// ---------------------------------------------------------------------------
__global__ __launch_bounds__(256) void k_softmax(float* __restrict__ E) {
  const int wave = threadIdx.x >> 6, lane = threadIdx.x & 63;
  float* p = E + ((size_t)blockIdx.x * 4 + wave) * NNODE + lane * 8;
  float4 v0 = *(float4*)p;
  float4 v1 = *(float4*)(p + 4);
  float mx = fmaxf(fmaxf(fmaxf(v0.x, v0.y), fmaxf(v0.z, v0.w)),
                   fmaxf(fmaxf(v1.x, v1.y), fmaxf(v1.z, v1.w)));
#pragma unroll
  for (int o = 32; o; o >>= 1) mx = fmaxf(mx, __shfl_xor(mx, o));
  v0.x = __expf(v0.x - mx); v0.y = __expf(v0.y - mx);
  v0.z = __expf(v0.z - mx); v0.w = __expf(v0.w - mx);
  v1.x = __expf(v1.x - mx); v1.y = __expf(v1.y - mx);
  v1.z = __expf(v1.z - mx); v1.w = __expf(v1.w - mx);
  float s = v0.x + v0.y + v0.z + v0.w + v1.x + v1.y + v1.z + v1.w;
#pragma unroll
  for (int o = 32; o; o >>= 1) s += __shfl_xor(s, o);
  const float inv = 1.0f / s;
  v0.x *= inv; v0.y *= inv; v0.z *= inv; v0.w *= inv;
  v1.x *= inv; v1.y *= inv; v1.z *= inv; v1.w *= inv;
  *(float4*)p = v0;
  *(float4*)(p + 4) = v1;
}

// ---------------------------------------------------------------------------
// K6: o = att @ hh_bh  [512,512]@[512,128] per (bb,h) -> R2 slice.
// ---------------------------------------------------------------------------
__global__ __launch_bounds__(256) void k_o(const float* __restrict__ E,
                                           const float* __restrict__ HH,
                                           float* __restrict__ O, int b0) {
  __shared__ float As[16][68], Bs[16][68];
  const int t = threadIdx.x, tx = t & 15, ty = t >> 4;
  const int rowBase = blockIdx.y * 64, colBase = blockIdx.x * 64;
  const int bb = blockIdx.z >> 2, h = blockIdx.z & 3;
  const float* Pb = E + (size_t)(bb * NHEAD + h) * NNODE * NNODE;
  const float* hb = HH + (size_t)(b0 + bb) * NNODE * OUTC + h * HDIM;
  float acc[4][4] = {};
  for (int k0 = 0; k0 < NNODE; k0 += 16) {
    {
      int r = t >> 2, kq = (t & 3) * 4;
      float4 va = *(const float4*)&Pb[(size_t)(rowBase + r) * NNODE + k0 + kq];
      As[kq + 0][r] = va.x; As[kq + 1][r] = va.y; As[kq + 2][r] = va.z; As[kq + 3][r] = va.w;
      int kk = t >> 4, c4 = (t & 15) * 4;
      *(float4*)&Bs[kk][c4] = *(const float4*)&hb[(size_t)(k0 + kk) * OUTC + colBase + c4];
    }
    __syncthreads();
#pragma unroll
    for (int kk = 0; kk < 16; ++kk) {
      float4 a4 = *(const float4*)&As[kk][ty * 4];
      float4 b4 = *(const float4*)&Bs[kk][tx * 4];
      float a[4] = {a4.x, a4.y, a4.z, a4.w};
      float b[4] = {b4.x, b4.y, b4.z, b4.w};
#pragma unroll
      for (int i = 0; i < 4; ++i)
#pragma unroll
        for (int j = 0; j < 4; ++j) acc[i][j] = fmaf(a[i], b[j], acc[i][j]);
    }
    __syncthreads();
  }
  float* Ob = O + (size_t)(b0 + bb) * NNODE * OUTC + h * HDIM;
#pragma unroll
  for (int i = 0; i < 4; ++i)
    *(float4*)&Ob[(size_t)(rowBase + ty * 4 + i) * OUTC + colBase + tx * 4] =
        make_float4(acc[i][0], acc[i][1], acc[i][2], acc[i][3]);
}

// ---------------------------------------------------------------------------
// K7a: cast o fp32 [32][512][512] -> fp16 padded [32][514][512] (1-row halo,
// zeroed) so the conv tap shift is an unconditional contiguous load.
// 4 rows per block, 64 threads/row, 8 channels/thread.
// ---------------------------------------------------------------------------
__global__ __launch_bounds__(256) void k_cast_pad(const float* __restrict__ O,
                                                  _Float16* __restrict__ OP) {
  const int gid = blockIdx.x * 256 + threadIdx.x;
  const int row = gid >> 6;               // 0 .. 32*514-1
  const int c8  = (gid & 63) * 8;
  const int b   = row / 514;
  const int n   = row - b * 514 - 1;      // -1 .. 512
  half8 h = {};
  if ((unsigned)n < (unsigned)NNODE) {
    const float* src = &O[(((size_t)b << 9) + n) * OUTC + c8];
    float4 v0 = *(const float4*)src;
    float4 v1 = *(const float4*)(src + 4);
    h[0] = (_Float16)v0.x; h[1] = (_Float16)v0.y;
    h[2] = (_Float16)v0.z; h[3] = (_Float16)v0.w;
    h[4] = (_Float16)v1.x; h[5] = (_Float16)v1.y;
    h[6] = (_Float16)v1.z; h[7] = (_Float16)v1.w;
  }
  *(half8*)&OP[(size_t)row * OUTC + c8] = h;
}

// ---------------------------------------------------------------------------
// K7b: conv_w [OUT][IN][3] fp32 -> Wt [OUT][3*IN] fp16, k-major (k=tap*512+ci)
// ---------------------------------------------------------------------------
__global__ __launch_bounds__(256) void k_wt(const float* __restrict__ CW,
                                            _Float16* __restrict__ WT) {
  const int gid = blockIdx.x * 256 + threadIdx.x;   // 512*1536 total
  const int n = gid / 1536;
  const int k = gid - n * 1536;
  const int tap = k >> 9, ci = k & 511;
  WT[gid] = (_Float16)CW[(size_t)n * 1536 + ci * 3 + tap];
}

// ---------------------------------------------------------------------------
// K7c: y = relu(bn2(conv + conv_b)) via fp16 MFMA GEMM.
// M=16384 rows (b,n), N=512 out-channels, K=1536 (tap-major).
// 128x128 tile, BK=32, global_load_lds(16B), mfma_f32_16x16x32_f16,
// 4 waves x (4x4 of 16x16) frags.
// ---------------------------------------------------------------------------
__global__ __launch_bounds__(256) void k_conv_mfma(
    const _Float16* __restrict__ OP,   // [32][514][512]
    const _Float16* __restrict__ WT,   // [512][1536]
    const float* __restrict__ cb, const float* __restrict__ g2,
    const float* __restrict__ b2, const float* __restrict__ m2,
    const float* __restrict__ v2, float* __restrict__ Y) {
  __shared__ _Float16 At[128 * 32];
  __shared__ _Float16 Bt[128 * 32];
  const int tid = threadIdx.x;
  const int lane = tid & 63, wave = tid >> 6;
  const int wr = (wave >> 1) * 64, wc = (wave & 1) * 64;
  const int rowBase = blockIdx.y * 128, colBase = blockIdx.x * 128;
  const int b = rowBase >> 9;          // 128 | 512 => whole tile in one batch
  const int n0 = rowBase & 511;
  const int r = tid >> 2;              // staging row 0..63
  const int ko = (tid & 3) * 8;        // staging k-offset (elements)
  floatx4 acc[4][4] = {};

  for (int k0 = 0; k0 < 3 * OUTC; k0 += 32) {
    const int tap = k0 >> 9;
    const int cib = k0 & 511;
    const size_t abase = ((size_t)b * 514 + n0 + tap) * OUTC + cib + ko;
    GLOBAL_TO_LDS16(&OP[abase + (size_t)r * OUTC],        &At[tid * 8]);
    GLOBAL_TO_LDS16(&OP[abase + (size_t)(r + 64) * OUTC], &At[2048 + tid * 8]);
    GLOBAL_TO_LDS16(&WT[(size_t)(colBase + r) * 1536 + k0 + ko],      &Bt[tid * 8]);
    GLOBAL_TO_LDS16(&WT[(size_t)(colBase + r + 64) * 1536 + k0 + ko], &Bt[2048 + tid * 8]);
    __syncthreads();
    const int fr = lane & 15, q = lane >> 4;
    half8 af[4], bf[4];
#pragma unroll
    for (int i = 0; i < 4; ++i)
      af[i] = *(const half8*)&At[(wr + i * 16 + fr) * 32 + q * 8];
#pragma unroll
    for (int j = 0; j < 4; ++j)
      bf[j] = *(const half8*)&Bt[(wc + j * 16 + fr) * 32 + q * 8];
#pragma unroll
    for (int i = 0; i < 4; ++i)
#pragma unroll
      for (int j = 0; j < 4; ++j)
        acc[i][j] = __builtin_amdgcn_mfma_f32_16x16x32_f16(af[i], bf[j], acc[i][j], 0, 0, 0);
    __syncthreads();
  }

  // Epilogue: D[row=q*4+reg][col=lane&15] per 16x16 frag; fused BN2+ReLU.
  const int fr = lane & 15, q = lane >> 4;
  float sc[4], of[4];
#pragma unroll
  for (int j = 0; j < 4; ++j) {
    int c = colBase + wc + j * 16 + fr;
    float s = g2[c] * rsqrtf(v2[c] + EPSV);
    sc[j] = s;
    of[j] = (cb[c] - m2[c]) * s + b2[c];
  }
#pragma unroll
  for (int i = 0; i < 4; ++i) {
    const int R0r = rowBase + wr + i * 16 + q * 4;
#pragma unroll
    for (int rg = 0; rg < 4; ++rg) {
      float* dst = &Y[(size_t)(R0r + rg) * OUTC + colBase + wc + fr];
#pragma unroll
      for (int j = 0; j < 4; ++j)
        dst[j * 16] = fmaxf(fmaf(acc[i][j][rg], sc[j], of[j]), 0.0f);
    }
  }
}

// ---------------------------------------------------------------------------
extern "C" void kernel_launch(void* const* d_in, const int* in_sizes, int n_in,
                              void* d_out, int out_size, void* d_ws, size_t ws_size,
                              hipStream_t stream) {
  const float* x     = (const float*)d_in[0];
  const float* adj   = (const float*)d_in[1];
  const float* gc_w  = (const float*)d_in[2];
  const float* gc_b  = (const float*)d_in[3];
  const float* bn1_g = (const float*)d_in[4];
  const float* bn1_b = (const float*)d_in[5];
  const float* bn1_m = (const float*)d_in[6];
  const float* bn1_v = (const float*)d_in[7];
  const float* gat_w = (const float*)d_in[8];
  const float* conv_w= (const float*)d_in[9];
  const float* conv_b= (const float*)d_in[10];
  const float* bn2_g = (const float*)d_in[11];
  const float* bn2_b = (const float*)d_in[12];
  const float* bn2_m = (const float*)d_in[13];
  const float* bn2_v = (const float*)d_in[14];
  float* out = (float*)d_out;

  // Workspace plan:
  //   R0 [33.5MB]: support, then hh
  //   R1 [33.5MB]: g, then e-chunks, then {O_pad fp16 (16.8MB) + Wt fp16 (1.6MB)}
  //   R2 [33.5MB]: o (full fp32, for conv)
  char* ws = (char*)d_ws;
  float* R0 = (float*)(ws);
  float* R1 = (float*)(ws + (size_t)33554432);
  float* R2 = (float*)(ws + (size_t)67108864);
  _Float16* OP = (_Float16*)(ws + (size_t)33554432);
  _Float16* WT = (_Float16*)(ws + (size_t)33554432 + 16842752);

  // K1: support = x @ gc_w -> R0
  k_support<<<dim3(4, 128), 256, 0, stream>>>(x, gc_w, R0);
  // K2: g = relu(bn1(adj @ support + gc_b)) -> R1
  k_gcn<<<dim3(4, 4, BATCH), 256, 0, stream>>>(adj, R0, R1, gc_b, bn1_g, bn1_b, bn1_m, bn1_v);
  // K3: hh = g @ gat_w^T -> R0
  k_hh<<<dim3(4, 128), 256, 0, stream>>>(R1, gat_w, R0);
  // K4-6: attention in 4 chunks of 8 batches (e-chunk lives in R1)
  for (int c = 0; c < 4; ++c) {
    int b0 = c * 8;
    k_e<<<dim3(4, 4, 32), 256, 0, stream>>>(R0, R1, b0);
    k_softmax<<<dim3(4096), 256, 0, stream>>>(R1);
    k_o<<<dim3(2, 8, 32), 256, 0, stream>>>(R1, R0, R2, b0);
  }
  // K7: cast+pad o, transform weights, fp16 MFMA conv + bn2 + relu -> out
  k_cast_pad<<<dim3((32 * 514 * 64) / 256), 256, 0, stream>>>(R2, OP);
  k_wt<<<dim3((512 * 1536) / 256), 256, 0, stream>>>(conv_w, WT);
  k_conv_mfma<<<dim3(4, 128), 256, 0, stream>>>(OP, WT, conv_b, bn2_g, bn2_b, bn2_m, bn2_v, out);
}

// Round 3
// 400.451 us; speedup vs baseline: 2.6577x; 1.8623x over previous
//
#include <hip/hip_runtime.h>
#include <math.h>

// Problem constants (B,N,F_IN,HID,OUT,H,D) = (32,512,256,512,512,4,128)
#define BATCH 32
#define NNODE 512
#define FIN   256
#define HIDC  512
#define OUTC  512
#define NHEAD 4
#define HDIM  128
#define EPSV  1e-5f
#define ALPHA_LR 0.2f

typedef _Float16 half8 __attribute__((ext_vector_type(8)));
typedef _Float16 half4v __attribute__((ext_vector_type(4)));
typedef float floatx4 __attribute__((ext_vector_type(4)));

#define GLOBAL_TO_LDS16(g, l)                                                  \
  __builtin_amdgcn_global_load_lds(                                            \
      (const __attribute__((address_space(1))) void*)(g),                      \
      (__attribute__((address_space(3))) void*)(l), 16, 0, 0)

// ---------------------------------------------------------------------------
// Generic 128x128 split-fp16 MFMA GEMM core. A ~ Ah+Al [M,K] row-major,
// B^T ~ Bh+Bl [N,K] row-major (k-contiguous). C += A@B via 3 MFMA products
// (Al*Bh + Ah*Bl + Ah*Bh), fp32 accum => ~22-bit effective input precision.
// BK=32, unpadded LDS tiles (global_load_lds 16B lane-contiguous layout).
// ---------------------------------------------------------------------------
__device__ __forceinline__ void split_gemm_acc(
    const _Float16* __restrict__ Ah, const _Float16* __restrict__ Al, int lda,
    const _Float16* __restrict__ Bh, const _Float16* __restrict__ Bl, int ldb,
    int K, int rowBase, int colBase,
    _Float16* sAh, _Float16* sAl, _Float16* sBh, _Float16* sBl,
    floatx4 acc[4][4], int tid) {
  const int lane = tid & 63, wave = tid >> 6;
  const int wr = (wave >> 1) * 64, wc = (wave & 1) * 64;
  const int fr = lane & 15, q = lane >> 4;
  const int r = tid >> 2, ko = (tid & 3) * 8;
  for (int k0 = 0; k0 < K; k0 += 32) {
    GLOBAL_TO_LDS16(&Ah[(size_t)(rowBase + r) * lda + k0 + ko], &sAh[tid * 8]);
    GLOBAL_TO_LDS16(&Ah[(size_t)(rowBase + r + 64) * lda + k0 + ko], &sAh[2048 + tid * 8]);
    GLOBAL_TO_LDS16(&Al[(size_t)(rowBase + r) * lda + k0 + ko], &sAl[tid * 8]);
    GLOBAL_TO_LDS16(&Al[(size_t)(rowBase + r + 64) * lda + k0 + ko], &sAl[2048 + tid * 8]);
    GLOBAL_TO_LDS16(&Bh[(size_t)(colBase + r) * ldb + k0 + ko], &sBh[tid * 8]);
    GLOBAL_TO_LDS16(&Bh[(size_t)(colBase + r + 64) * ldb + k0 + ko], &sBh[2048 + tid * 8]);
    GLOBAL_TO_LDS16(&Bl[(size_t)(colBase + r) * ldb + k0 + ko], &sBl[tid * 8]);
    GLOBAL_TO_LDS16(&Bl[(size_t)(colBase + r + 64) * ldb + k0 + ko], &sBl[2048 + tid * 8]);
    __syncthreads();
    half8 ah[4], al4[4], bh[4], bl4[4];
#pragma unroll
    for (int i = 0; i < 4; ++i) {
      ah[i]  = *(const half8*)&sAh[(wr + i * 16 + fr) * 32 + q * 8];
      al4[i] = *(const half8*)&sAl[(wr + i * 16 + fr) * 32 + q * 8];
    }
#pragma unroll
    for (int j = 0; j < 4; ++j) {
      bh[j]  = *(const half8*)&sBh[(wc + j * 16 + fr) * 32 + q * 8];
      bl4[j] = *(const half8*)&sBl[(wc + j * 16 + fr) * 32 + q * 8];
    }
#pragma unroll
    for (int i = 0; i < 4; ++i)
#pragma unroll
      for (int j = 0; j < 4; ++j) {
        acc[i][j] = __builtin_amdgcn_mfma_f32_16x16x32_f16(al4[i], bh[j], acc[i][j], 0, 0, 0);
        acc[i][j] = __builtin_amdgcn_mfma_f32_16x16x32_f16(ah[i], bl4[j], acc[i][j], 0, 0, 0);
        acc[i][j] = __builtin_amdgcn_mfma_f32_16x16x32_f16(ah[i], bh[j], acc[i][j], 0, 0, 0);
      }
    __syncthreads();
  }
}

// ---------------------------------------------------------------------------
// Prep: split adj, gc_w^T, gat_w into fp16 hi/lo; conv weights -> k-major
// fp16; zero OP halo rows. One grid-striped elementwise kernel.
// Segments: adj[0,262144) gcwt[262144,393216) gatw[393216,655360)
//           WT[655360,1441792) halo[1441792,1474560)
// ---------------------------------------------------------------------------
__global__ __launch_bounds__(256) void k_prep(
    const float* __restrict__ adj, const float* __restrict__ gcw,
    const float* __restrict__ gatw, const float* __restrict__ cw,
    _Float16* __restrict__ ADJh, _Float16* __restrict__ ADJl,
    _Float16* __restrict__ GWh, _Float16* __restrict__ GWl,
    _Float16* __restrict__ GAh, _Float16* __restrict__ GAl,
    _Float16* __restrict__ WT, _Float16* __restrict__ OP) {
  const int i = blockIdx.x * 256 + threadIdx.x;
  if (i < 262144) {
    float v = adj[i];
    _Float16 h = (_Float16)v;
    ADJh[i] = h; ADJl[i] = (_Float16)(v - (float)h);
  } else if (i < 393216) {
    int j = i - 262144;
    int n = j >> 8, k = j & 255;
    float v = gcw[(size_t)k * HIDC + n];       // transpose: gcwt[n][k]
    _Float16 h = (_Float16)v;
    GWh[j] = h; GWl[j] = (_Float16)(v - (float)h);
  } else if (i < 655360) {
    int j = i - 393216;
    float v = gatw[j];                          // [h*128+d][hid] already B^T
    _Float16 h = (_Float16)v;
    GAh[j] = h; GAl[j] = (_Float16)(v - (float)h);
  } else if (i < 1441792) {
    int j = i - 655360;
    int n = j / 1536, kk = j - n * 1536;
    int tap = kk >> 9, ci = kk & 511;
    WT[j] = (_Float16)cw[(size_t)n * 1536 + ci * 3 + tap];
  } else if (i < 1474560) {
    int j = i - 1441792;
    int b = j >> 10, rs = (j >> 9) & 1, c = j & 511;
    OP[((size_t)b * 514 + rs * 513) * OUTC + c] = (_Float16)0.f;
  }
}

// x [16384,256] fp32 -> hi/lo fp16
__global__ __launch_bounds__(256) void k_xsplit(const float* __restrict__ X,
                                                _Float16* __restrict__ Xh,
                                                _Float16* __restrict__ Xl) {
  const int i = (blockIdx.x * 256 + threadIdx.x) * 4;
  float4 v = *(const float4*)&X[i];
  half4v h, l;
  h[0] = (_Float16)v.x; l[0] = (_Float16)(v.x - (float)h[0]);
  h[1] = (_Float16)v.y; l[1] = (_Float16)(v.y - (float)h[1]);
  h[2] = (_Float16)v.z; l[2] = (_Float16)(v.z - (float)h[2]);
  h[3] = (_Float16)v.w; l[3] = (_Float16)(v.w - (float)h[3]);
  *(half4v*)&Xh[i] = h;
  *(half4v*)&Xl[i] = l;
}

// ---------------------------------------------------------------------------
// support^T = gc_w^T @ x^T : M=512(ch) N=16384(bn) K=256. Split output.
// ---------------------------------------------------------------------------
__global__ __launch_bounds__(256) void k_support_t(
    const _Float16* __restrict__ GWh, const _Float16* __restrict__ GWl,
    const _Float16* __restrict__ Xh, const _Float16* __restrict__ Xl,
    _Float16* __restrict__ STh, _Float16* __restrict__ STl) {
  __shared__ _Float16 sm[4][4096];
  const int tid = threadIdx.x;
  const int rowBase = blockIdx.y * 128, colBase = blockIdx.x * 128;
  floatx4 acc[4][4] = {};
  split_gemm_acc(GWh, GWl, FIN, Xh, Xl, FIN, FIN, rowBase, colBase,
                 sm[0], sm[1], sm[2], sm[3], acc, tid);
  const int lane = tid & 63, wave = tid >> 6;
  const int wr = (wave >> 1) * 64, wc = (wave & 1) * 64;
  const int fr = lane & 15, q = lane >> 4;
#pragma unroll
  for (int i = 0; i < 4; ++i) {
    const int ch0 = rowBase + wr + i * 16 + q * 4;
#pragma unroll
    for (int rg = 0; rg < 4; ++rg) {
      size_t base = (size_t)(ch0 + rg) * 16384 + colBase + wc + fr;
#pragma unroll
      for (int j = 0; j < 4; ++j) {
        float v = acc[i][j][rg];
        _Float16 h = (_Float16)v;
        STh[base + j * 16] = h;
        STl[base + j * 16] = (_Float16)(v - (float)h);
      }
    }
  }
}

// ---------------------------------------------------------------------------
// g = relu(bn1(adj @ support_b + gc_b)) per batch. Split output.
// A=adj [512,512]; B^T = support_t[ch][b*512+node] ld 16384.
// ---------------------------------------------------------------------------
__global__ __launch_bounds__(256) void k_gcn(
    const _Float16* __restrict__ ADJh, const _Float16* __restrict__ ADJl,
    const _Float16* __restrict__ STh, const _Float16* __restrict__ STl,
    const float* __restrict__ gcb, const float* __restrict__ g1,
    const float* __restrict__ b1, const float* __restrict__ m1,
    const float* __restrict__ v1,
    _Float16* __restrict__ Gh, _Float16* __restrict__ Gl) {
  __shared__ _Float16 sm[4][4096];
  const int tid = threadIdx.x;
  const int rowBase = blockIdx.y * 128, colBase = blockIdx.x * 128;
  const int b = blockIdx.z;
  floatx4 acc[4][4] = {};
  split_gemm_acc(ADJh, ADJl, NNODE, STh + (size_t)b * NNODE, STl + (size_t)b * NNODE,
                 16384, NNODE, rowBase, colBase, sm[0], sm[1], sm[2], sm[3], acc, tid);
  const int lane = tid & 63, wave = tid >> 6;
  const int wr = (wave >> 1) * 64, wc = (wave & 1) * 64;
  const int fr = lane & 15, q = lane >> 4;
  float sc[4], of[4];
#pragma unroll
  for (int j = 0; j < 4; ++j) {
    int c = colBase + wc + j * 16 + fr;
    float s = g1[c] * rsqrtf(v1[c] + EPSV);
    sc[j] = s;
    of[j] = (gcb[c] - m1[c]) * s + b1[c];
  }
#pragma unroll
  for (int i = 0; i < 4; ++i) {
    const int n0 = rowBase + wr + i * 16 + q * 4;
#pragma unroll
    for (int rg = 0; rg < 4; ++rg) {
      size_t base = ((size_t)b * NNODE + n0 + rg) * HIDC + colBase + wc + fr;
#pragma unroll
      for (int j = 0; j < 4; ++j) {
        float v = fmaxf(fmaf(acc[i][j][rg], sc[j], of[j]), 0.0f);
        _Float16 h = (_Float16)v;
        Gh[base + j * 16] = h;
        Gl[base + j * 16] = (_Float16)(v - (float)h);
      }
    }
  }
}

// ---------------------------------------------------------------------------
// hh = g @ gat_w^T : M=16384 N=512 K=512. Split output.
// ---------------------------------------------------------------------------
__global__ __launch_bounds__(256) void k_hh(
    const _Float16* __restrict__ Gh, const _Float16* __restrict__ Gl,
    const _Float16* __restrict__ GAh, const _Float16* __restrict__ GAl,
    _Float16* __restrict__ HHh, _Float16* __restrict__ HHl) {
  __shared__ _Float16 sm[4][4096];
  const int tid = threadIdx.x;
  const int rowBase = blockIdx.y * 128, colBase = blockIdx.x * 128;
  floatx4 acc[4][4] = {};
  split_gemm_acc(Gh, Gl, HIDC, GAh, GAl, HIDC, HIDC, rowBase, colBase,
                 sm[0], sm[1], sm[2], sm[3], acc, tid);
  const int lane = tid & 63, wave = tid >> 6;
  const int wr = (wave >> 1) * 64, wc = (wave & 1) * 64;
  const int fr = lane & 15, q = lane >> 4;
#pragma unroll
  for (int i = 0; i < 4; ++i) {
    const int r0 = rowBase + wr + i * 16 + q * 4;
#pragma unroll
    for (int rg = 0; rg < 4; ++rg) {
      size_t base = (size_t)(r0 + rg) * OUTC + colBase + wc + fr;
#pragma unroll
      for (int j = 0; j < 4; ++j) {
        float v = acc[i][j][rg];
        _Float16 h = (_Float16)v;
        HHh[base + j * 16] = h;
        HHl[base + j * 16] = (_Float16)(v - (float)h);
      }
    }
  }
}

// ---------------------------------------------------------------------------
// e = leakyrelu(hh_bh @ hh_bh^T) for head h, all 32 batches. K=128. fp32 out.
// ---------------------------------------------------------------------------
__global__ __launch_bounds__(256) void k_e(
    const _Float16* __restrict__ HHh, const _Float16* __restrict__ HHl,
    float* __restrict__ E, int h) {
  __shared__ _Float16 sm[4][4096];
  const int tid = threadIdx.x;
  const int rowBase = blockIdx.y * 128, colBase = blockIdx.x * 128;
  const int bb = blockIdx.z;
  const _Float16* Ah = HHh + (size_t)bb * NNODE * OUTC + h * HDIM;
  const _Float16* Al = HHl + (size_t)bb * NNODE * OUTC + h * HDIM;
  floatx4 acc[4][4] = {};
  split_gemm_acc(Ah, Al, OUTC, Ah, Al, OUTC, HDIM, rowBase, colBase,
                 sm[0], sm[1], sm[2], sm[3], acc, tid);
  const int lane = tid & 63, wave = tid >> 6;
  const int wr = (wave >> 1) * 64, wc = (wave & 1) * 64;
  const int fr = lane & 15, q = lane >> 4;
  float* Eb = E + (size_t)bb * NNODE * NNODE;
#pragma unroll
  for (int i = 0; i < 4; ++i) {
    const int r0 = rowBase + wr + i * 16 + q * 4;
#pragma unroll
    for (int rg = 0; rg < 4; ++rg) {
      float* dst = &Eb[(size_t)(r0 + rg) * NNODE + colBase + wc + fr];
#pragma unroll
      for (int j = 0; j < 4; ++j) {
        float v = acc[i][j][rg];
        dst[j * 16] = v > 0.0f ? v : ALPHA_LR * v;
      }
    }
  }
}

// ---------------------------------------------------------------------------
// Row softmax fp32 -> fp16 att IN PLACE (att row aliases e row start; k_o
// reads with ld=1024 fp16). One wave per row.
// ---------------------------------------------------------------------------
__global__ __launch_bounds__(256) void k_softmax(float* __restrict__ E) {
  const int wave = threadIdx.x >> 6, lane = threadIdx.x & 63;
  const size_t row = (size_t)blockIdx.x * 4 + wave;
  float* p = E + row * NNODE + lane * 8;
  float4 v0 = *(float4*)p;
  float4 v1 = *(float4*)(p + 4);
  float mx = fmaxf(fmaxf(fmaxf(v0.x, v0.y), fmaxf(v0.z, v0.w)),
                   fmaxf(fmaxf(v1.x, v1.y), fmaxf(v1.z, v1.w)));
#pragma unroll
  for (int o = 32; o; o >>= 1) mx = fmaxf(mx, __shfl_xor(mx, o));
  v0.x = __expf(v0.x - mx); v0.y = __expf(v0.y - mx);
  v0.z = __expf(v0.z - mx); v0.w = __expf(v0.w - mx);
  v1.x = __expf(v1.x - mx); v1.y = __expf(v1.y - mx);
  v1.z = __expf(v1.z - mx); v1.w = __expf(v1.w - mx);
  float s = v0.x + v0.y + v0.z + v0.w + v1.x + v1.y + v1.z + v1.w;
#pragma unroll
  for (int o = 32; o; o >>= 1) s += __shfl_xor(s, o);
  const float inv = 1.0f / s;
  _Float16* ap = (_Float16*)(E + row * NNODE) + lane * 8;
  half8 hv;
  hv[0] = (_Float16)(v0.x * inv); hv[1] = (_Float16)(v0.y * inv);
  hv[2] = (_Float16)(v0.z * inv); hv[3] = (_Float16)(v0.w * inv);
  hv[4] = (_Float16)(v1.x * inv); hv[5] = (_Float16)(v1.y * inv);
  hv[6] = (_Float16)(v1.z * inv); hv[7] = (_Float16)(v1.w * inv);
  *(half8*)ap = hv;
}

// ---------------------------------------------------------------------------
// o = att @ hh_bh (plain fp16 MFMA; post-softmax, no amplification).
// Tile 64x128, K=512. B staged via LDS transpose (hh is [node][d], need
// [d][node]). Output written directly into padded conv input OP fp16.
// ---------------------------------------------------------------------------
__global__ __launch_bounds__(256) void k_o(const float* __restrict__ E,
                                           const _Float16* __restrict__ HHh,
                                           _Float16* __restrict__ OP, int h) {
  __shared__ _Float16 sA[64 * 32];
  __shared__ _Float16 sB[128 * 32];
  const int tid = threadIdx.x;
  const int lane = tid & 63, wave = tid >> 6;
  const int wr = (wave >> 1) * 32, wc = (wave & 1) * 64;
  const int fr = lane & 15, q = lane >> 4;
  const int rowBase = blockIdx.x * 64;
  const int bb = blockIdx.y;
  const _Float16* ATT = (const _Float16*)E + (size_t)bb * NNODE * 1024;
  const _Float16* HB = HHh + (size_t)bb * NNODE * OUTC + h * HDIM;
  const int r = tid >> 2, ko = (tid & 3) * 8;
  const int mB = tid >> 3, d0 = (tid & 7) * 16;
  floatx4 acc[2][4] = {};
  for (int k0 = 0; k0 < NNODE; k0 += 32) {
    GLOBAL_TO_LDS16(&ATT[(size_t)(rowBase + r) * 1024 + k0 + ko], &sA[tid * 8]);
    const _Float16* src = &HB[(size_t)(k0 + mB) * OUTC + d0];
    half8 v0 = *(const half8*)src;
    half8 v1 = *(const half8*)(src + 8);
#pragma unroll
    for (int e2 = 0; e2 < 8; ++e2) {
      sB[(d0 + e2) * 32 + mB] = v0[e2];
      sB[(d0 + 8 + e2) * 32 + mB] = v1[e2];
    }
    __syncthreads();
    half8 af[2], bf[4];
#pragma unroll
    for (int i = 0; i < 2; ++i)
      af[i] = *(const half8*)&sA[(wr + i * 16 + fr) * 32 + q * 8];
#pragma unroll
    for (int j = 0; j < 4; ++j)
      bf[j] = *(const half8*)&sB[(wc + j * 16 + fr) * 32 + q * 8];
#pragma unroll
    for (int i = 0; i < 2; ++i)
#pragma unroll
      for (int j = 0; j < 4; ++j)
        acc[i][j] = __builtin_amdgcn_mfma_f32_16x16x32_f16(af[i], bf[j], acc[i][j], 0, 0, 0);
    __syncthreads();
  }
#pragma unroll
  for (int i = 0; i < 2; ++i)
#pragma unroll
    for (int rg = 0; rg < 4; ++rg) {
      int node = rowBase + wr + i * 16 + q * 4 + rg;
      size_t base = ((size_t)bb * 514 + 1 + node) * OUTC + h * HDIM + wc + fr;
#pragma unroll
      for (int j = 0; j < 4; ++j)
        OP[base + j * 16] = (_Float16)acc[i][j][rg];
    }
}

// ---------------------------------------------------------------------------
// y = relu(bn2(conv1d(o)+conv_b)) via fp16 MFMA GEMM (unchanged from R2).
// ---------------------------------------------------------------------------
__global__ __launch_bounds__(256) void k_conv_mfma(
    const _Float16* __restrict__ OP, const _Float16* __restrict__ WT,
    const float* __restrict__ cb, const float* __restrict__ g2,
    const float* __restrict__ b2, const float* __restrict__ m2,
    const float* __restrict__ v2, float* __restrict__ Y) {
  __shared__ _Float16 At[128 * 32];
  __shared__ _Float16 Bt[128 * 32];
  const int tid = threadIdx.x;
  const int lane = tid & 63, wave = tid >> 6;
  const int wr = (wave >> 1) * 64, wc = (wave & 1) * 64;
  const int rowBase = blockIdx.y * 128, colBase = blockIdx.x * 128;
  const int b = rowBase >> 9;
  const int n0 = rowBase & 511;
  const int r = tid >> 2;
  const int ko = (tid & 3) * 8;
  floatx4 acc[4][4] = {};
  for (int k0 = 0; k0 < 3 * OUTC; k0 += 32) {
    const int tap = k0 >> 9;
    const int cib = k0 & 511;
    const size_t abase = ((size_t)b * 514 + n0 + tap) * OUTC + cib + ko;
    GLOBAL_TO_LDS16(&OP[abase + (size_t)r * OUTC],        &At[tid * 8]);
    GLOBAL_TO_LDS16(&OP[abase + (size_t)(r + 64) * OUTC], &At[2048 + tid * 8]);
    GLOBAL_TO_LDS16(&WT[(size_t)(colBase + r) * 1536 + k0 + ko],      &Bt[tid * 8]);
    GLOBAL_TO_LDS16(&WT[(size_t)(colBase + r + 64) * 1536 + k0 + ko], &Bt[2048 + tid * 8]);
    __syncthreads();
    const int fr = lane & 15, q = lane >> 4;
    half8 af[4], bf[4];
#pragma unroll
    for (int i = 0; i < 4; ++i)
      af[i] = *(const half8*)&At[(wr + i * 16 + fr) * 32 + q * 8];
#pragma unroll
    for (int j = 0; j < 4; ++j)
      bf[j] = *(const half8*)&Bt[(wc + j * 16 + fr) * 32 + q * 8];
#pragma unroll
    for (int i = 0; i < 4; ++i)
#pragma unroll
      for (int j = 0; j < 4; ++j)
        acc[i][j] = __builtin_amdgcn_mfma_f32_16x16x32_f16(af[i], bf[j], acc[i][j], 0, 0, 0);
    __syncthreads();
  }
  const int fr = lane & 15, q = lane >> 4;
  float sc[4], of[4];
#pragma unroll
  for (int j = 0; j < 4; ++j) {
    int c = colBase + wc + j * 16 + fr;
    float s = g2[c] * rsqrtf(v2[c] + EPSV);
    sc[j] = s;
    of[j] = (cb[c] - m2[c]) * s + b2[c];
  }
#pragma unroll
  for (int i = 0; i < 4; ++i) {
    const int R0r = rowBase + wr + i * 16 + q * 4;
#pragma unroll
    for (int rg = 0; rg < 4; ++rg) {
      float* dst = &Y[(size_t)(R0r + rg) * OUTC + colBase + wc + fr];
#pragma unroll
      for (int j = 0; j < 4; ++j)
        dst[j * 16] = fmaxf(fmaf(acc[i][j][rg], sc[j], of[j]), 0.0f);
    }
  }
}

// ---------------------------------------------------------------------------
extern "C" void kernel_launch(void* const* d_in, const int* in_sizes, int n_in,
                              void* d_out, int out_size, void* d_ws, size_t ws_size,
                              hipStream_t stream) {
  const float* x     = (const float*)d_in[0];
  const float* adj   = (const float*)d_in[1];
  const float* gc_w  = (const float*)d_in[2];
  const float* gc_b  = (const float*)d_in[3];
  const float* bn1_g = (const float*)d_in[4];
  const float* bn1_b = (const float*)d_in[5];
  const float* bn1_m = (const float*)d_in[6];
  const float* bn1_v = (const float*)d_in[7];
  const float* gat_w = (const float*)d_in[8];
  const float* conv_w= (const float*)d_in[9];
  const float* conv_b= (const float*)d_in[10];
  const float* bn2_g = (const float*)d_in[11];
  const float* bn2_b = (const float*)d_in[12];
  const float* bn2_m = (const float*)d_in[13];
  const float* bn2_v = (const float*)d_in[14];
  float* out = (float*)d_out;

  // Lifetime-packed workspace (96 MiB):
  //  [0,16M):      st_hi   -> hh_hi
  //  [16M,32M):    st_lo   -> hh_lo
  //  [32M,64M):    x_hi+x_lo -> g_hi(@32M)+g_lo(@48M) -> e fp32 (32MiB/head)
  //  [64M,80.07M): OP fp16 padded conv input
  //  [80.07M..):   WT, adj/gcwt/gatw hi/lo splits
  char* ws = (char*)d_ws;
  _Float16* STh = (_Float16*)(ws + 0);
  _Float16* STl = (_Float16*)(ws + 16777216);
  _Float16* HHh = (_Float16*)(ws + 0);
  _Float16* HHl = (_Float16*)(ws + 16777216);
  _Float16* Xh  = (_Float16*)(ws + 33554432);
  _Float16* Xl  = (_Float16*)(ws + 41943040);
  _Float16* Gh  = (_Float16*)(ws + 33554432);
  _Float16* Gl  = (_Float16*)(ws + 50331648);
  float*    E   = (float*)   (ws + 33554432);
  _Float16* OP  = (_Float16*)(ws + 67108864);
  _Float16* WT  = (_Float16*)(ws + 83951616);
  _Float16* ADJh= (_Float16*)(ws + 85524480);
  _Float16* ADJl= (_Float16*)(ws + 86048768);
  _Float16* GWh = (_Float16*)(ws + 86573056);
  _Float16* GWl = (_Float16*)(ws + 86835200);
  _Float16* GAh = (_Float16*)(ws + 87097344);
  _Float16* GAl = (_Float16*)(ws + 87621632);

  k_prep<<<5760, 256, 0, stream>>>(adj, gc_w, gat_w, conv_w,
                                   ADJh, ADJl, GWh, GWl, GAh, GAl, WT, OP);
  k_xsplit<<<4096, 256, 0, stream>>>(x, Xh, Xl);
  k_support_t<<<dim3(128, 4), 256, 0, stream>>>(GWh, GWl, Xh, Xl, STh, STl);
  k_gcn<<<dim3(4, 4, 32), 256, 0, stream>>>(ADJh, ADJl, STh, STl, gc_b,
                                            bn1_g, bn1_b, bn1_m, bn1_v, Gh, Gl);
  k_hh<<<dim3(4, 128), 256, 0, stream>>>(Gh, Gl, GAh, GAl, HHh, HHl);
  for (int h = 0; h < NHEAD; ++h) {
    k_e<<<dim3(4, 4, 32), 256, 0, stream>>>(HHh, HHl, E, h);
    k_softmax<<<4096, 256, 0, stream>>>(E);
    k_o<<<dim3(8, 32), 256, 0, stream>>>(E, HHh, OP, h);
  }
  k_conv_mfma<<<dim3(4, 128), 256, 0, stream>>>(OP, WT, conv_b,
                                                bn2_g, bn2_b, bn2_m, bn2_v, out);
}

// Round 4
// 302.352 us; speedup vs baseline: 3.5201x; 1.3245x over previous
//
#include <hip/hip_runtime.h>
#include <math.h>

// Problem constants (B,N,F_IN,HID,OUT,H,D) = (32,512,256,512,512,4,128)
#define BATCH 32
#define NNODE 512
#define FIN   256
#define HIDC  512
#define OUTC  512
#define NHEAD 4
#define HDIM  128
#define EPSV  1e-5f
#define ALPHA_LR 0.2f

typedef _Float16 half8 __attribute__((ext_vector_type(8)));
typedef _Float16 half4v __attribute__((ext_vector_type(4)));
typedef float floatx4 __attribute__((ext_vector_type(4)));

#define GLOBAL_TO_LDS16(g, l)                                                  \
  __builtin_amdgcn_global_load_lds(                                            \
      (const __attribute__((address_space(1))) void*)(g),                      \
      (__attribute__((address_space(3))) void*)(l), 16, 0, 0)

// ---------------------------------------------------------------------------
// Generic 128x128 split-fp16 MFMA GEMM core. A ~ Ah+Al [M,K] row-major,
// B^T ~ Bh+Bl [N,K] row-major (k-contiguous). 3 MFMA products, fp32 accum.
// ---------------------------------------------------------------------------
__device__ __forceinline__ void split_gemm_acc(
    const _Float16* __restrict__ Ah, const _Float16* __restrict__ Al, int lda,
    const _Float16* __restrict__ Bh, const _Float16* __restrict__ Bl, int ldb,
    int K, int rowBase, int colBase,
    _Float16* sAh, _Float16* sAl, _Float16* sBh, _Float16* sBl,
    floatx4 acc[4][4], int tid) {
  const int lane = tid & 63, wave = tid >> 6;
  const int wr = (wave >> 1) * 64, wc = (wave & 1) * 64;
  const int fr = lane & 15, q = lane >> 4;
  const int r = tid >> 2, ko = (tid & 3) * 8;
  for (int k0 = 0; k0 < K; k0 += 32) {
    GLOBAL_TO_LDS16(&Ah[(size_t)(rowBase + r) * lda + k0 + ko], &sAh[tid * 8]);
    GLOBAL_TO_LDS16(&Ah[(size_t)(rowBase + r + 64) * lda + k0 + ko], &sAh[2048 + tid * 8]);
    GLOBAL_TO_LDS16(&Al[(size_t)(rowBase + r) * lda + k0 + ko], &sAl[tid * 8]);
    GLOBAL_TO_LDS16(&Al[(size_t)(rowBase + r + 64) * lda + k0 + ko], &sAl[2048 + tid * 8]);
    GLOBAL_TO_LDS16(&Bh[(size_t)(colBase + r) * ldb + k0 + ko], &sBh[tid * 8]);
    GLOBAL_TO_LDS16(&Bh[(size_t)(colBase + r + 64) * ldb + k0 + ko], &sBh[2048 + tid * 8]);
    GLOBAL_TO_LDS16(&Bl[(size_t)(colBase + r) * ldb + k0 + ko], &sBl[tid * 8]);
    GLOBAL_TO_LDS16(&Bl[(size_t)(colBase + r + 64) * ldb + k0 + ko], &sBl[2048 + tid * 8]);
    __syncthreads();
    half8 ah[4], al4[4], bh[4], bl4[4];
#pragma unroll
    for (int i = 0; i < 4; ++i) {
      ah[i]  = *(const half8*)&sAh[(wr + i * 16 + fr) * 32 + q * 8];
      al4[i] = *(const half8*)&sAl[(wr + i * 16 + fr) * 32 + q * 8];
    }
#pragma unroll
    for (int j = 0; j < 4; ++j) {
      bh[j]  = *(const half8*)&sBh[(wc + j * 16 + fr) * 32 + q * 8];
      bl4[j] = *(const half8*)&sBl[(wc + j * 16 + fr) * 32 + q * 8];
    }
#pragma unroll
    for (int i = 0; i < 4; ++i)
#pragma unroll
      for (int j = 0; j < 4; ++j) {
        acc[i][j] = __builtin_amdgcn_mfma_f32_16x16x32_f16(al4[i], bh[j], acc[i][j], 0, 0, 0);
        acc[i][j] = __builtin_amdgcn_mfma_f32_16x16x32_f16(ah[i], bl4[j], acc[i][j], 0, 0, 0);
        acc[i][j] = __builtin_amdgcn_mfma_f32_16x16x32_f16(ah[i], bh[j], acc[i][j], 0, 0, 0);
      }
    __syncthreads();
  }
}

// ---------------------------------------------------------------------------
// Prep: split adj, gc_w^T, gat_w into fp16 hi/lo; conv weights -> k-major
// fp16; zero OP halo rows.
// ---------------------------------------------------------------------------
__global__ __launch_bounds__(256) void k_prep(
    const float* __restrict__ adj, const float* __restrict__ gcw,
    const float* __restrict__ gatw, const float* __restrict__ cw,
    _Float16* __restrict__ ADJh, _Float16* __restrict__ ADJl,
    _Float16* __restrict__ GWh, _Float16* __restrict__ GWl,
    _Float16* __restrict__ GAh, _Float16* __restrict__ GAl,
    _Float16* __restrict__ WT, _Float16* __restrict__ OP) {
  const int i = blockIdx.x * 256 + threadIdx.x;
  if (i < 262144) {
    float v = adj[i];
    _Float16 h = (_Float16)v;
    ADJh[i] = h; ADJl[i] = (_Float16)(v - (float)h);
  } else if (i < 393216) {
    int j = i - 262144;
    int n = j >> 8, k = j & 255;
    float v = gcw[(size_t)k * HIDC + n];       // transpose: gcwt[n][k]
    _Float16 h = (_Float16)v;
    GWh[j] = h; GWl[j] = (_Float16)(v - (float)h);
  } else if (i < 655360) {
    int j = i - 393216;
    float v = gatw[j];                          // [h*128+d][hid] already B^T
    _Float16 h = (_Float16)v;
    GAh[j] = h; GAl[j] = (_Float16)(v - (float)h);
  } else if (i < 1441792) {
    int j = i - 655360;
    int n = j / 1536, kk = j - n * 1536;
    int tap = kk >> 9, ci = kk & 511;
    WT[j] = (_Float16)cw[(size_t)n * 1536 + ci * 3 + tap];
  } else if (i < 1474560) {
    int j = i - 1441792;
    int b = j >> 10, rs = (j >> 9) & 1, c = j & 511;
    OP[((size_t)b * 514 + rs * 513) * OUTC + c] = (_Float16)0.f;
  }
}

// x [16384,256] fp32 -> hi/lo fp16
__global__ __launch_bounds__(256) void k_xsplit(const float* __restrict__ X,
                                                _Float16* __restrict__ Xh,
                                                _Float16* __restrict__ Xl) {
  const int i = (blockIdx.x * 256 + threadIdx.x) * 4;
  float4 v = *(const float4*)&X[i];
  half4v h, l;
  h[0] = (_Float16)v.x; l[0] = (_Float16)(v.x - (float)h[0]);
  h[1] = (_Float16)v.y; l[1] = (_Float16)(v.y - (float)h[1]);
  h[2] = (_Float16)v.z; l[2] = (_Float16)(v.z - (float)h[2]);
  h[3] = (_Float16)v.w; l[3] = (_Float16)(v.w - (float)h[3]);
  *(half4v*)&Xh[i] = h;
  *(half4v*)&Xl[i] = l;
}

// ---------------------------------------------------------------------------
// support^T = gc_w^T @ x^T : M=512(ch) N=16384(bn) K=256. Split output.
// ---------------------------------------------------------------------------
__global__ __launch_bounds__(256) void k_support_t(
    const _Float16* __restrict__ GWh, const _Float16* __restrict__ GWl,
    const _Float16* __restrict__ Xh, const _Float16* __restrict__ Xl,
    _Float16* __restrict__ STh, _Float16* __restrict__ STl) {
  __shared__ _Float16 sm[4][4096];
  const int tid = threadIdx.x;
  const int rowBase = blockIdx.y * 128, colBase = blockIdx.x * 128;
  floatx4 acc[4][4] = {};
  split_gemm_acc(GWh, GWl, FIN, Xh, Xl, FIN, FIN, rowBase, colBase,
                 sm[0], sm[1], sm[2], sm[3], acc, tid);
  const int lane = tid & 63, wave = tid >> 6;
  const int wr = (wave >> 1) * 64, wc = (wave & 1) * 64;
  const int fr = lane & 15, q = lane >> 4;
#pragma unroll
  for (int i = 0; i < 4; ++i) {
    const int ch0 = rowBase + wr + i * 16 + q * 4;
#pragma unroll
    for (int rg = 0; rg < 4; ++rg) {
      size_t base = (size_t)(ch0 + rg) * 16384 + colBase + wc + fr;
#pragma unroll
      for (int j = 0; j < 4; ++j) {
        float v = acc[i][j][rg];
        _Float16 h = (_Float16)v;
        STh[base + j * 16] = h;
        STl[base + j * 16] = (_Float16)(v - (float)h);
      }
    }
  }
}

// ---------------------------------------------------------------------------
// g = relu(bn1(adj @ support_b + gc_b)) per batch. Split output.
// ---------------------------------------------------------------------------
__global__ __launch_bounds__(256) void k_gcn(
    const _Float16* __restrict__ ADJh, const _Float16* __restrict__ ADJl,
    const _Float16* __restrict__ STh, const _Float16* __restrict__ STl,
    const float* __restrict__ gcb, const float* __restrict__ g1,
    const float* __restrict__ b1, const float* __restrict__ m1,
    const float* __restrict__ v1,
    _Float16* __restrict__ Gh, _Float16* __restrict__ Gl) {
  __shared__ _Float16 sm[4][4096];
  const int tid = threadIdx.x;
  const int rowBase = blockIdx.y * 128, colBase = blockIdx.x * 128;
  const int b = blockIdx.z;
  floatx4 acc[4][4] = {};
  split_gemm_acc(ADJh, ADJl, NNODE, STh + (size_t)b * NNODE, STl + (size_t)b * NNODE,
                 16384, NNODE, rowBase, colBase, sm[0], sm[1], sm[2], sm[3], acc, tid);
  const int lane = tid & 63, wave = tid >> 6;
  const int wr = (wave >> 1) * 64, wc = (wave & 1) * 64;
  const int fr = lane & 15, q = lane >> 4;
  float sc[4], of[4];
#pragma unroll
  for (int j = 0; j < 4; ++j) {
    int c = colBase + wc + j * 16 + fr;
    float s = g1[c] * rsqrtf(v1[c] + EPSV);
    sc[j] = s;
    of[j] = (gcb[c] - m1[c]) * s + b1[c];
  }
#pragma unroll
  for (int i = 0; i < 4; ++i) {
    const int n0 = rowBase + wr + i * 16 + q * 4;
#pragma unroll
    for (int rg = 0; rg < 4; ++rg) {
      size_t base = ((size_t)b * NNODE + n0 + rg) * HIDC + colBase + wc + fr;
#pragma unroll
      for (int j = 0; j < 4; ++j) {
        float v = fmaxf(fmaf(acc[i][j][rg], sc[j], of[j]), 0.0f);
        _Float16 h = (_Float16)v;
        Gh[base + j * 16] = h;
        Gl[base + j * 16] = (_Float16)(v - (float)h);
      }
    }
  }
}

// ---------------------------------------------------------------------------
// hh = g @ gat_w^T : M=16384 N=512 K=512. Split output.
// ---------------------------------------------------------------------------
__global__ __launch_bounds__(256) void k_hh(
    const _Float16* __restrict__ Gh, const _Float16* __restrict__ Gl,
    const _Float16* __restrict__ GAh, const _Float16* __restrict__ GAl,
    _Float16* __restrict__ HHh, _Float16* __restrict__ HHl) {
  __shared__ _Float16 sm[4][4096];
  const int tid = threadIdx.x;
  const int rowBase = blockIdx.y * 128, colBase = blockIdx.x * 128;
  floatx4 acc[4][4] = {};
  split_gemm_acc(Gh, Gl, HIDC, GAh, GAl, HIDC, HIDC, rowBase, colBase,
                 sm[0], sm[1], sm[2], sm[3], acc, tid);
  const int lane = tid & 63, wave = tid >> 6;
  const int wr = (wave >> 1) * 64, wc = (wave & 1) * 64;
  const int fr = lane & 15, q = lane >> 4;
#pragma unroll
  for (int i = 0; i < 4; ++i) {
    const int r0 = rowBase + wr + i * 16 + q * 4;
#pragma unroll
    for (int rg = 0; rg < 4; ++rg) {
      size_t base = (size_t)(r0 + rg) * OUTC + colBase + wc + fr;
#pragma unroll
      for (int j = 0; j < 4; ++j) {
        float v = acc[i][j][rg];
        _Float16 h = (_Float16)v;
        HHh[base + j * 16] = h;
        HHl[base + j * 16] = (_Float16)(v - (float)h);
      }
    }
  }
}

// ---------------------------------------------------------------------------
// Fused flash attention per (q-tile, bb, h): S = leakyrelu(Q K^T) in
// split-fp16 (3-MFMA), online softmax in registers (row-reduce via shfl_xor
// across the 16 fr-lanes), P fp16 -> LDS (stride 136), O += P V in plain
// fp16, O /= l written straight into padded conv input OP.
// Wave w owns q-rows [w*32, w*32+32). 74 KB LDS -> 2 blocks/CU.
// ---------------------------------------------------------------------------
__global__ __launch_bounds__(256, 2) void k_attn(
    const _Float16* __restrict__ HHh, const _Float16* __restrict__ HHl,
    _Float16* __restrict__ OP) {
  __shared__ _Float16 sQh[128 * 32], sQl[128 * 32];
  __shared__ _Float16 sKh[128 * 32], sKl[128 * 32];
  __shared__ _Float16 sP[128 * 136];
  __shared__ _Float16 sVT[128 * 32];
  const int tid = threadIdx.x;
  const int lane = tid & 63, wave = tid >> 6;
  const int fr = lane & 15, q = lane >> 4;
  const int qBase = blockIdx.x * 128;
  const int bb = blockIdx.y, h = blockIdx.z;
  const int w32 = wave * 32;
  const _Float16* Qh = HHh + ((size_t)bb * NNODE) * OUTC + h * HDIM;
  const _Float16* Ql = HHl + ((size_t)bb * NNODE) * OUTC + h * HDIM;
  const int r = tid >> 2, ko = (tid & 3) * 8;
  const int mB = tid >> 3, d0 = (tid & 7) * 16;

  floatx4 oacc[2][8] = {};
  float m_i[2][4], l_i[2][4];
#pragma unroll
  for (int i = 0; i < 2; ++i)
#pragma unroll
    for (int rg = 0; rg < 4; ++rg) { m_i[i][rg] = -1e30f; l_i[i][rg] = 0.f; }

  for (int kt = 0; kt < 4; ++kt) {
    // ---- S = Q @ K^T (split-fp16), K-tile rows kt*128.. ----
    floatx4 sacc[2][8] = {};
    for (int k0 = 0; k0 < HDIM; k0 += 32) {
      GLOBAL_TO_LDS16(&Qh[(size_t)(qBase + r) * OUTC + k0 + ko], &sQh[tid * 8]);
      GLOBAL_TO_LDS16(&Qh[(size_t)(qBase + r + 64) * OUTC + k0 + ko], &sQh[2048 + tid * 8]);
      GLOBAL_TO_LDS16(&Ql[(size_t)(qBase + r) * OUTC + k0 + ko], &sQl[tid * 8]);
      GLOBAL_TO_LDS16(&Ql[(size_t)(qBase + r + 64) * OUTC + k0 + ko], &sQl[2048 + tid * 8]);
      GLOBAL_TO_LDS16(&Qh[(size_t)(kt * 128 + r) * OUTC + k0 + ko], &sKh[tid * 8]);
      GLOBAL_TO_LDS16(&Qh[(size_t)(kt * 128 + r + 64) * OUTC + k0 + ko], &sKh[2048 + tid * 8]);
      GLOBAL_TO_LDS16(&Ql[(size_t)(kt * 128 + r) * OUTC + k0 + ko], &sKl[tid * 8]);
      GLOBAL_TO_LDS16(&Ql[(size_t)(kt * 128 + r + 64) * OUTC + k0 + ko], &sKl[2048 + tid * 8]);
      __syncthreads();
      half8 ah[2], al2[2];
#pragma unroll
      for (int i = 0; i < 2; ++i) {
        ah[i]  = *(const half8*)&sQh[(w32 + i * 16 + fr) * 32 + q * 8];
        al2[i] = *(const half8*)&sQl[(w32 + i * 16 + fr) * 32 + q * 8];
      }
#pragma unroll
      for (int j = 0; j < 8; ++j) {
        half8 bh = *(const half8*)&sKh[(j * 16 + fr) * 32 + q * 8];
        half8 bl = *(const half8*)&sKl[(j * 16 + fr) * 32 + q * 8];
#pragma unroll
        for (int i = 0; i < 2; ++i) {
          sacc[i][j] = __builtin_amdgcn_mfma_f32_16x16x32_f16(al2[i], bh, sacc[i][j], 0, 0, 0);
          sacc[i][j] = __builtin_amdgcn_mfma_f32_16x16x32_f16(ah[i], bl, sacc[i][j], 0, 0, 0);
          sacc[i][j] = __builtin_amdgcn_mfma_f32_16x16x32_f16(ah[i], bh, sacc[i][j], 0, 0, 0);
        }
      }
      __syncthreads();
    }
    // ---- LeakyReLU + online softmax; P -> LDS ----
#pragma unroll
    for (int i = 0; i < 2; ++i)
#pragma unroll
      for (int j = 0; j < 8; ++j)
#pragma unroll
        for (int rg = 0; rg < 4; ++rg) {
          float v = sacc[i][j][rg];
          sacc[i][j][rg] = v > 0.f ? v : ALPHA_LR * v;
        }
#pragma unroll
    for (int i = 0; i < 2; ++i)
#pragma unroll
      for (int rg = 0; rg < 4; ++rg) {
        float mx = sacc[i][0][rg];
#pragma unroll
        for (int j = 1; j < 8; ++j) mx = fmaxf(mx, sacc[i][j][rg]);
        mx = fmaxf(mx, __shfl_xor(mx, 1));
        mx = fmaxf(mx, __shfl_xor(mx, 2));
        mx = fmaxf(mx, __shfl_xor(mx, 4));
        mx = fmaxf(mx, __shfl_xor(mx, 8));
        float mnew = fmaxf(m_i[i][rg], mx);
        float alpha = __expf(m_i[i][rg] - mnew);
        m_i[i][rg] = mnew;
        const int row = w32 + i * 16 + q * 4 + rg;
        float sum = 0.f;
#pragma unroll
        for (int j = 0; j < 8; ++j) {
          float p = __expf(sacc[i][j][rg] - mnew);
          sum += p;
          sP[row * 136 + j * 16 + fr] = (_Float16)p;
        }
        sum += __shfl_xor(sum, 1);
        sum += __shfl_xor(sum, 2);
        sum += __shfl_xor(sum, 4);
        sum += __shfl_xor(sum, 8);
        l_i[i][rg] = l_i[i][rg] * alpha + sum;
#pragma unroll
        for (int j = 0; j < 8; ++j) oacc[i][j][rg] *= alpha;
      }
    // ---- O += P @ V (plain fp16; V = K-tile, transposed in LDS) ----
    for (int ks = 0; ks < 4; ++ks) {
      __syncthreads();
      {
        const _Float16* src = &Qh[(size_t)(kt * 128 + ks * 32 + mB) * OUTC + d0];
        half8 v0 = *(const half8*)src;
        half8 v1 = *(const half8*)(src + 8);
#pragma unroll
        for (int e2 = 0; e2 < 8; ++e2) {
          sVT[(d0 + e2) * 32 + mB] = v0[e2];
          sVT[(d0 + 8 + e2) * 32 + mB] = v1[e2];
        }
      }
      __syncthreads();
      half8 pa[2];
#pragma unroll
      for (int i = 0; i < 2; ++i)
        pa[i] = *(const half8*)&sP[(w32 + i * 16 + fr) * 136 + ks * 32 + q * 8];
#pragma unroll
      for (int j = 0; j < 8; ++j) {
        half8 bv = *(const half8*)&sVT[(j * 16 + fr) * 32 + q * 8];
#pragma unroll
        for (int i = 0; i < 2; ++i)
          oacc[i][j] = __builtin_amdgcn_mfma_f32_16x16x32_f16(pa[i], bv, oacc[i][j], 0, 0, 0);
      }
    }
    __syncthreads();
  }
  // ---- normalize + write into padded conv input ----
#pragma unroll
  for (int i = 0; i < 2; ++i)
#pragma unroll
    for (int rg = 0; rg < 4; ++rg) {
      const float inv = 1.0f / l_i[i][rg];
      const int node = qBase + w32 + i * 16 + q * 4 + rg;
      size_t base = ((size_t)bb * 514 + 1 + node) * OUTC + h * HDIM + fr;
#pragma unroll
      for (int j = 0; j < 8; ++j)
        OP[base + j * 16] = (_Float16)(oacc[i][j][rg] * inv);
    }
}

// ---------------------------------------------------------------------------
// y = relu(bn2(conv1d(o)+conv_b)) via fp16 MFMA GEMM, XCD-swizzled so each
// XCD's resident blocks share A row-tiles in its local L2.
// ---------------------------------------------------------------------------
__global__ __launch_bounds__(256) void k_conv_mfma(
    const _Float16* __restrict__ OP, const _Float16* __restrict__ WT,
    const float* __restrict__ cb, const float* __restrict__ g2,
    const float* __restrict__ b2, const float* __restrict__ m2,
    const float* __restrict__ v2, float* __restrict__ Y) {
  __shared__ _Float16 At[128 * 32];
  __shared__ _Float16 Bt[128 * 32];
  const int tid = threadIdx.x;
  const int lane = tid & 63, wave = tid >> 6;
  const int wr = (wave >> 1) * 64, wc = (wave & 1) * 64;
  // XCD swizzle: id%8 = XCD; each XCD gets 16 contiguous row-tiles x 4 cols.
  const int id = blockIdx.y * 4 + blockIdx.x;
  const int jj = id >> 3;
  const int rowBase = ((id & 7) * 16 + (jj >> 2)) * 128;
  const int colBase = (jj & 3) * 128;
  const int b = rowBase >> 9;
  const int n0 = rowBase & 511;
  const int r = tid >> 2;
  const int ko = (tid & 3) * 8;
  floatx4 acc[4][4] = {};
  for (int k0 = 0; k0 < 3 * OUTC; k0 += 32) {
    const int tap = k0 >> 9;
    const int cib = k0 & 511;
    const size_t abase = ((size_t)b * 514 + n0 + tap) * OUTC + cib + ko;
    GLOBAL_TO_LDS16(&OP[abase + (size_t)r * OUTC],        &At[tid * 8]);
    GLOBAL_TO_LDS16(&OP[abase + (size_t)(r + 64) * OUTC], &At[2048 + tid * 8]);
    GLOBAL_TO_LDS16(&WT[(size_t)(colBase + r) * 1536 + k0 + ko],      &Bt[tid * 8]);
    GLOBAL_TO_LDS16(&WT[(size_t)(colBase + r + 64) * 1536 + k0 + ko], &Bt[2048 + tid * 8]);
    __syncthreads();
    const int fr = lane & 15, q = lane >> 4;
    half8 af[4], bf[4];
#pragma unroll
    for (int i = 0; i < 4; ++i)
      af[i] = *(const half8*)&At[(wr + i * 16 + fr) * 32 + q * 8];
#pragma unroll
    for (int j = 0; j < 4; ++j)
      bf[j] = *(const half8*)&Bt[(wc + j * 16 + fr) * 32 + q * 8];
#pragma unroll
    for (int i = 0; i < 4; ++i)
#pragma unroll
      for (int j = 0; j < 4; ++j)
        acc[i][j] = __builtin_amdgcn_mfma_f32_16x16x32_f16(af[i], bf[j], acc[i][j], 0, 0, 0);
    __syncthreads();
  }
  const int fr = lane & 15, q = lane >> 4;
  float sc[4], of[4];
#pragma unroll
  for (int j = 0; j < 4; ++j) {
    int c = colBase + wc + j * 16 + fr;
    float s = g2[c] * rsqrtf(v2[c] + EPSV);
    sc[j] = s;
    of[j] = (cb[c] - m2[c]) * s + b2[c];
  }
#pragma unroll
  for (int i = 0; i < 4; ++i) {
    const int R0r = rowBase + wr + i * 16 + q * 4;
#pragma unroll
    for (int rg = 0; rg < 4; ++rg) {
      float* dst = &Y[(size_t)(R0r + rg) * OUTC + colBase + wc + fr];
#pragma unroll
      for (int j = 0; j < 4; ++j)
        dst[j * 16] = fmaxf(fmaf(acc[i][j][rg], sc[j], of[j]), 0.0f);
    }
  }
}

// ---------------------------------------------------------------------------
extern "C" void kernel_launch(void* const* d_in, const int* in_sizes, int n_in,
                              void* d_out, int out_size, void* d_ws, size_t ws_size,
                              hipStream_t stream) {
  const float* x     = (const float*)d_in[0];
  const float* adj   = (const float*)d_in[1];
  const float* gc_w  = (const float*)d_in[2];
  const float* gc_b  = (const float*)d_in[3];
  const float* bn1_g = (const float*)d_in[4];
  const float* bn1_b = (const float*)d_in[5];
  const float* bn1_m = (const float*)d_in[6];
  const float* bn1_v = (const float*)d_in[7];
  const float* gat_w = (const float*)d_in[8];
  const float* conv_w= (const float*)d_in[9];
  const float* conv_b= (const float*)d_in[10];
  const float* bn2_g = (const float*)d_in[11];
  const float* bn2_b = (const float*)d_in[12];
  const float* bn2_m = (const float*)d_in[13];
  const float* bn2_v = (const float*)d_in[14];
  float* out = (float*)d_out;

  // Lifetime-packed workspace (96 MiB):
  //  [0,16M):      st_hi   -> hh_hi
  //  [16M,32M):    st_lo   -> hh_lo
  //  [32M,64M):    x_hi+x_lo -> g_hi(@32M)+g_lo(@48M)
  //  [64M,80.07M): OP fp16 padded conv input
  //  [80.07M..):   WT, adj/gcwt/gatw hi/lo splits
  char* ws = (char*)d_ws;
  _Float16* STh = (_Float16*)(ws + 0);
  _Float16* STl = (_Float16*)(ws + 16777216);
  _Float16* HHh = (_Float16*)(ws + 0);
  _Float16* HHl = (_Float16*)(ws + 16777216);
  _Float16* Xh  = (_Float16*)(ws + 33554432);
  _Float16* Xl  = (_Float16*)(ws + 41943040);
  _Float16* Gh  = (_Float16*)(ws + 33554432);
  _Float16* Gl  = (_Float16*)(ws + 50331648);
  _Float16* OP  = (_Float16*)(ws + 67108864);
  _Float16* WT  = (_Float16*)(ws + 83951616);
  _Float16* ADJh= (_Float16*)(ws + 85524480);
  _Float16* ADJl= (_Float16*)(ws + 86048768);
  _Float16* GWh = (_Float16*)(ws + 86573056);
  _Float16* GWl = (_Float16*)(ws + 86835200);
  _Float16* GAh = (_Float16*)(ws + 87097344);
  _Float16* GAl = (_Float16*)(ws + 87621632);

  k_prep<<<5760, 256, 0, stream>>>(adj, gc_w, gat_w, conv_w,
                                   ADJh, ADJl, GWh, GWl, GAh, GAl, WT, OP);
  k_xsplit<<<4096, 256, 0, stream>>>(x, Xh, Xl);
  k_support_t<<<dim3(128, 4), 256, 0, stream>>>(GWh, GWl, Xh, Xl, STh, STl);
  k_gcn<<<dim3(4, 4, 32), 256, 0, stream>>>(ADJh, ADJl, STh, STl, gc_b,
                                            bn1_g, bn1_b, bn1_m, bn1_v, Gh, Gl);
  k_hh<<<dim3(4, 128), 256, 0, stream>>>(Gh, Gl, GAh, GAl, HHh, HHl);
  k_attn<<<dim3(4, BATCH, NHEAD), 256, 0, stream>>>(HHh, HHl, OP);
  k_conv_mfma<<<dim3(4, 128), 256, 0, stream>>>(OP, WT, conv_b,
                                                bn2_g, bn2_b, bn2_m, bn2_v, out);
}

// Round 5
// 296.724 us; speedup vs baseline: 3.5868x; 1.0190x over previous
//
#include <hip/hip_runtime.h>
#include <math.h>

// Problem constants (B,N,F_IN,HID,OUT,H,D) = (32,512,256,512,512,4,128)
#define BATCH 32
#define NNODE 512
#define FIN   256
#define HIDC  512
#define OUTC  512
#define NHEAD 4
#define HDIM  128
#define EPSV  1e-5f
#define ALPHA_LR 0.2f

typedef _Float16 half8 __attribute__((ext_vector_type(8)));
typedef _Float16 half4v __attribute__((ext_vector_type(4)));
typedef float floatx4 __attribute__((ext_vector_type(4)));

#define GLOBAL_TO_LDS16(g, l)                                                  \
  __builtin_amdgcn_global_load_lds(                                            \
      (const __attribute__((address_space(1))) void*)(g),                      \
      (__attribute__((address_space(3))) void*)(l), 16, 0, 0)

// ---------------------------------------------------------------------------
// Generic 128x128 split-fp16 MFMA GEMM core. A ~ Ah+Al [M,K] row-major,
// B^T ~ Bh+Bl [N,K] row-major (k-contiguous). 3 MFMA products, fp32 accum.
// ---------------------------------------------------------------------------
__device__ __forceinline__ void split_gemm_acc(
    const _Float16* __restrict__ Ah, const _Float16* __restrict__ Al, int lda,
    const _Float16* __restrict__ Bh, const _Float16* __restrict__ Bl, int ldb,
    int K, int rowBase, int colBase,
    _Float16* sAh, _Float16* sAl, _Float16* sBh, _Float16* sBl,
    floatx4 acc[4][4], int tid) {
  const int lane = tid & 63, wave = tid >> 6;
  const int wr = (wave >> 1) * 64, wc = (wave & 1) * 64;
  const int fr = lane & 15, q = lane >> 4;
  const int r = tid >> 2, ko = (tid & 3) * 8;
  for (int k0 = 0; k0 < K; k0 += 32) {
    GLOBAL_TO_LDS16(&Ah[(size_t)(rowBase + r) * lda + k0 + ko], &sAh[tid * 8]);
    GLOBAL_TO_LDS16(&Ah[(size_t)(rowBase + r + 64) * lda + k0 + ko], &sAh[2048 + tid * 8]);
    GLOBAL_TO_LDS16(&Al[(size_t)(rowBase + r) * lda + k0 + ko], &sAl[tid * 8]);
    GLOBAL_TO_LDS16(&Al[(size_t)(rowBase + r + 64) * lda + k0 + ko], &sAl[2048 + tid * 8]);
    GLOBAL_TO_LDS16(&Bh[(size_t)(colBase + r) * ldb + k0 + ko], &sBh[tid * 8]);
    GLOBAL_TO_LDS16(&Bh[(size_t)(colBase + r + 64) * ldb + k0 + ko], &sBh[2048 + tid * 8]);
    GLOBAL_TO_LDS16(&Bl[(size_t)(colBase + r) * ldb + k0 + ko], &sBl[tid * 8]);
    GLOBAL_TO_LDS16(&Bl[(size_t)(colBase + r + 64) * ldb + k0 + ko], &sBl[2048 + tid * 8]);
    __syncthreads();
    half8 ah[4], al4[4], bh[4], bl4[4];
#pragma unroll
    for (int i = 0; i < 4; ++i) {
      ah[i]  = *(const half8*)&sAh[(wr + i * 16 + fr) * 32 + q * 8];
      al4[i] = *(const half8*)&sAl[(wr + i * 16 + fr) * 32 + q * 8];
    }
#pragma unroll
    for (int j = 0; j < 4; ++j) {
      bh[j]  = *(const half8*)&sBh[(wc + j * 16 + fr) * 32 + q * 8];
      bl4[j] = *(const half8*)&sBl[(wc + j * 16 + fr) * 32 + q * 8];
    }
#pragma unroll
    for (int i = 0; i < 4; ++i)
#pragma unroll
      for (int j = 0; j < 4; ++j) {
        acc[i][j] = __builtin_amdgcn_mfma_f32_16x16x32_f16(al4[i], bh[j], acc[i][j], 0, 0, 0);
        acc[i][j] = __builtin_amdgcn_mfma_f32_16x16x32_f16(ah[i], bl4[j], acc[i][j], 0, 0, 0);
        acc[i][j] = __builtin_amdgcn_mfma_f32_16x16x32_f16(ah[i], bh[j], acc[i][j], 0, 0, 0);
      }
    __syncthreads();
  }
}

// ---------------------------------------------------------------------------
// Prep: split adj, gc_w^T, gat_w into fp16 hi/lo; conv weights -> k-major
// fp16; zero OP halo rows.
// ---------------------------------------------------------------------------
__global__ __launch_bounds__(256) void k_prep(
    const float* __restrict__ adj, const float* __restrict__ gcw,
    const float* __restrict__ gatw, const float* __restrict__ cw,
    _Float16* __restrict__ ADJh, _Float16* __restrict__ ADJl,
    _Float16* __restrict__ GWh, _Float16* __restrict__ GWl,
    _Float16* __restrict__ GAh, _Float16* __restrict__ GAl,
    _Float16* __restrict__ WT, _Float16* __restrict__ OP) {
  const int i = blockIdx.x * 256 + threadIdx.x;
  if (i < 262144) {
    float v = adj[i];
    _Float16 h = (_Float16)v;
    ADJh[i] = h; ADJl[i] = (_Float16)(v - (float)h);
  } else if (i < 393216) {
    int j = i - 262144;
    int n = j >> 8, k = j & 255;
    float v = gcw[(size_t)k * HIDC + n];       // transpose: gcwt[n][k]
    _Float16 h = (_Float16)v;
    GWh[j] = h; GWl[j] = (_Float16)(v - (float)h);
  } else if (i < 655360) {
    int j = i - 393216;
    float v = gatw[j];                          // [h*128+d][hid] already B^T
    _Float16 h = (_Float16)v;
    GAh[j] = h; GAl[j] = (_Float16)(v - (float)h);
  } else if (i < 1441792) {
    int j = i - 655360;
    int n = j / 1536, kk = j - n * 1536;
    int tap = kk >> 9, ci = kk & 511;
    WT[j] = (_Float16)cw[(size_t)n * 1536 + ci * 3 + tap];
  } else if (i < 1474560) {
    int j = i - 1441792;
    int b = j >> 10, rs = (j >> 9) & 1, c = j & 511;
    OP[((size_t)b * 514 + rs * 513) * OUTC + c] = (_Float16)0.f;
  }
}

// x [16384,256] fp32 -> hi/lo fp16
__global__ __launch_bounds__(256) void k_xsplit(const float* __restrict__ X,
                                                _Float16* __restrict__ Xh,
                                                _Float16* __restrict__ Xl) {
  const int i = (blockIdx.x * 256 + threadIdx.x) * 4;
  float4 v = *(const float4*)&X[i];
  half4v h, l;
  h[0] = (_Float16)v.x; l[0] = (_Float16)(v.x - (float)h[0]);
  h[1] = (_Float16)v.y; l[1] = (_Float16)(v.y - (float)h[1]);
  h[2] = (_Float16)v.z; l[2] = (_Float16)(v.z - (float)h[2]);
  h[3] = (_Float16)v.w; l[3] = (_Float16)(v.w - (float)h[3]);
  *(half4v*)&Xh[i] = h;
  *(half4v*)&Xl[i] = l;
}

// ---------------------------------------------------------------------------
// support^T = gc_w^T @ x^T : M=512(ch) N=16384(bn) K=256. Split output.
// ---------------------------------------------------------------------------
__global__ __launch_bounds__(256) void k_support_t(
    const _Float16* __restrict__ GWh, const _Float16* __restrict__ GWl,
    const _Float16* __restrict__ Xh, const _Float16* __restrict__ Xl,
    _Float16* __restrict__ STh, _Float16* __restrict__ STl) {
  __shared__ _Float16 sm[4][4096];
  const int tid = threadIdx.x;
  const int rowBase = blockIdx.y * 128, colBase = blockIdx.x * 128;
  floatx4 acc[4][4] = {};
  split_gemm_acc(GWh, GWl, FIN, Xh, Xl, FIN, FIN, rowBase, colBase,
                 sm[0], sm[1], sm[2], sm[3], acc, tid);
  const int lane = tid & 63, wave = tid >> 6;
  const int wr = (wave >> 1) * 64, wc = (wave & 1) * 64;
  const int fr = lane & 15, q = lane >> 4;
#pragma unroll
  for (int i = 0; i < 4; ++i) {
    const int ch0 = rowBase + wr + i * 16 + q * 4;
#pragma unroll
    for (int rg = 0; rg < 4; ++rg) {
      size_t base = (size_t)(ch0 + rg) * 16384 + colBase + wc + fr;
#pragma unroll
      for (int j = 0; j < 4; ++j) {
        float v = acc[i][j][rg];
        _Float16 h = (_Float16)v;
        STh[base + j * 16] = h;
        STl[base + j * 16] = (_Float16)(v - (float)h);
      }
    }
  }
}

// ---------------------------------------------------------------------------
// g = relu(bn1(adj @ support_b + gc_b)) per batch. Split output.
// ---------------------------------------------------------------------------
__global__ __launch_bounds__(256) void k_gcn(
    const _Float16* __restrict__ ADJh, const _Float16* __restrict__ ADJl,
    const _Float16* __restrict__ STh, const _Float16* __restrict__ STl,
    const float* __restrict__ gcb, const float* __restrict__ g1,
    const float* __restrict__ b1, const float* __restrict__ m1,
    const float* __restrict__ v1,
    _Float16* __restrict__ Gh, _Float16* __restrict__ Gl) {
  __shared__ _Float16 sm[4][4096];
  const int tid = threadIdx.x;
  const int rowBase = blockIdx.y * 128, colBase = blockIdx.x * 128;
  const int b = blockIdx.z;
  floatx4 acc[4][4] = {};
  split_gemm_acc(ADJh, ADJl, NNODE, STh + (size_t)b * NNODE, STl + (size_t)b * NNODE,
                 16384, NNODE, rowBase, colBase, sm[0], sm[1], sm[2], sm[3], acc, tid);
  const int lane = tid & 63, wave = tid >> 6;
  const int wr = (wave >> 1) * 64, wc = (wave & 1) * 64;
  const int fr = lane & 15, q = lane >> 4;
  float sc[4], of[4];
#pragma unroll
  for (int j = 0; j < 4; ++j) {
    int c = colBase + wc + j * 16 + fr;
    float s = g1[c] * rsqrtf(v1[c] + EPSV);
    sc[j] = s;
    of[j] = (gcb[c] - m1[c]) * s + b1[c];
  }
#pragma unroll
  for (int i = 0; i < 4; ++i) {
    const int n0 = rowBase + wr + i * 16 + q * 4;
#pragma unroll
    for (int rg = 0; rg < 4; ++rg) {
      size_t base = ((size_t)b * NNODE + n0 + rg) * HIDC + colBase + wc + fr;
#pragma unroll
      for (int j = 0; j < 4; ++j) {
        float v = fmaxf(fmaf(acc[i][j][rg], sc[j], of[j]), 0.0f);
        _Float16 h = (_Float16)v;
        Gh[base + j * 16] = h;
        Gl[base + j * 16] = (_Float16)(v - (float)h);
      }
    }
  }
}

// ---------------------------------------------------------------------------
// hh = g @ gat_w^T : M=16384 N=512 K=512. Split output.
// ---------------------------------------------------------------------------
__global__ __launch_bounds__(256) void k_hh(
    const _Float16* __restrict__ Gh, const _Float16* __restrict__ Gl,
    const _Float16* __restrict__ GAh, const _Float16* __restrict__ GAl,
    _Float16* __restrict__ HHh, _Float16* __restrict__ HHl) {
  __shared__ _Float16 sm[4][4096];
  const int tid = threadIdx.x;
  const int rowBase = blockIdx.y * 128, colBase = blockIdx.x * 128;
  floatx4 acc[4][4] = {};
  split_gemm_acc(Gh, Gl, HIDC, GAh, GAl, HIDC, HIDC, rowBase, colBase,
                 sm[0], sm[1], sm[2], sm[3], acc, tid);
  const int lane = tid & 63, wave = tid >> 6;
  const int wr = (wave >> 1) * 64, wc = (wave & 1) * 64;
  const int fr = lane & 15, q = lane >> 4;
#pragma unroll
  for (int i = 0; i < 4; ++i) {
    const int r0 = rowBase + wr + i * 16 + q * 4;
#pragma unroll
    for (int rg = 0; rg < 4; ++rg) {
      size_t base = (size_t)(r0 + rg) * OUTC + colBase + wc + fr;
#pragma unroll
      for (int j = 0; j < 4; ++j) {
        float v = acc[i][j][rg];
        _Float16 h = (_Float16)v;
        HHh[base + j * 16] = h;
        HHl[base + j * 16] = (_Float16)(v - (float)h);
      }
    }
  }
}

// ---------------------------------------------------------------------------
// Fused flash attention per (q-tile, bb, h). Q fragments live in registers
// (loaded once); K staged per kt via global_load_lds; V re-read through L2
// (XCD swizzle makes the (bb,h) slice L2-resident). Online softmax in
// registers; P fp16 via LDS (stride 136); O written into padded conv input.
// LDS = 58 KB -> 2 blocks/CU.
// ---------------------------------------------------------------------------
__global__ __launch_bounds__(256, 2) void k_attn(
    const _Float16* __restrict__ HHh, const _Float16* __restrict__ HHl,
    _Float16* __restrict__ OP) {
  __shared__ _Float16 sKh[128 * 32], sKl[128 * 32];
  __shared__ _Float16 sP[128 * 136];
  __shared__ _Float16 sVT[128 * 32];
  const int tid = threadIdx.x;
  const int lane = tid & 63, wave = tid >> 6;
  const int fr = lane & 15, q = lane >> 4;
  // XCD swizzle: blocks go to XCD id%8; give all 4 q-tiles of one (bb,h)
  // the same residue so the 256KB K/V slice stays in that XCD's L2.
  const int id = blockIdx.x;
  const int slot = id >> 3;
  const int g = (id & 7) + 8 * (slot >> 2);   // (bb,h) group, 0..127
  const int qBase = (slot & 3) * 128;
  const int bb = g >> 2, h = g & 3;
  const int w32 = wave * 32;
  const _Float16* Qh = HHh + ((size_t)bb * NNODE) * OUTC + h * HDIM;
  const _Float16* Ql = HHl + ((size_t)bb * NNODE) * OUTC + h * HDIM;
  const int r = tid >> 2, ko = (tid & 3) * 8;
  const int mB = tid >> 3, d0 = (tid & 7) * 16;

  // Q fragments in registers, loaded once (A layout: m=fr, k=q*8+j per k0).
  half8 qh[2][4], ql[2][4];
#pragma unroll
  for (int i = 0; i < 2; ++i)
#pragma unroll
    for (int k0 = 0; k0 < 4; ++k0) {
      const size_t off = (size_t)(qBase + w32 + i * 16 + fr) * OUTC + k0 * 32 + q * 8;
      qh[i][k0] = *(const half8*)&Qh[off];
      ql[i][k0] = *(const half8*)&Ql[off];
    }

  floatx4 oacc[2][8] = {};
  float m_i[2][4], l_i[2][4];
#pragma unroll
  for (int i = 0; i < 2; ++i)
#pragma unroll
    for (int rg = 0; rg < 4; ++rg) { m_i[i][rg] = -1e30f; l_i[i][rg] = 0.f; }

  for (int kt = 0; kt < 4; ++kt) {
    // ---- S = Q @ K^T (split-fp16) ----
    floatx4 sacc[2][8] = {};
#pragma unroll
    for (int k0 = 0; k0 < 4; ++k0) {
      GLOBAL_TO_LDS16(&Qh[(size_t)(kt * 128 + r) * OUTC + k0 * 32 + ko], &sKh[tid * 8]);
      GLOBAL_TO_LDS16(&Qh[(size_t)(kt * 128 + r + 64) * OUTC + k0 * 32 + ko], &sKh[2048 + tid * 8]);
      GLOBAL_TO_LDS16(&Ql[(size_t)(kt * 128 + r) * OUTC + k0 * 32 + ko], &sKl[tid * 8]);
      GLOBAL_TO_LDS16(&Ql[(size_t)(kt * 128 + r + 64) * OUTC + k0 * 32 + ko], &sKl[2048 + tid * 8]);
      __syncthreads();
#pragma unroll
      for (int j = 0; j < 8; ++j) {
        half8 bh = *(const half8*)&sKh[(j * 16 + fr) * 32 + q * 8];
        half8 bl = *(const half8*)&sKl[(j * 16 + fr) * 32 + q * 8];
#pragma unroll
        for (int i = 0; i < 2; ++i) {
          sacc[i][j] = __builtin_amdgcn_mfma_f32_16x16x32_f16(ql[i][k0], bh, sacc[i][j], 0, 0, 0);
          sacc[i][j] = __builtin_amdgcn_mfma_f32_16x16x32_f16(qh[i][k0], bl, sacc[i][j], 0, 0, 0);
          sacc[i][j] = __builtin_amdgcn_mfma_f32_16x16x32_f16(qh[i][k0], bh, sacc[i][j], 0, 0, 0);
        }
      }
      __syncthreads();
    }
    // ---- LeakyReLU + online softmax; P -> LDS (wave-private rows) ----
#pragma unroll
    for (int i = 0; i < 2; ++i)
#pragma unroll
      for (int j = 0; j < 8; ++j)
#pragma unroll
        for (int rg = 0; rg < 4; ++rg) {
          float v = sacc[i][j][rg];
          sacc[i][j][rg] = v > 0.f ? v : ALPHA_LR * v;
        }
#pragma unroll
    for (int i = 0; i < 2; ++i)
#pragma unroll
      for (int rg = 0; rg < 4; ++rg) {
        float mx = sacc[i][0][rg];
#pragma unroll
        for (int j = 1; j < 8; ++j) mx = fmaxf(mx, sacc[i][j][rg]);
        mx = fmaxf(mx, __shfl_xor(mx, 1));
        mx = fmaxf(mx, __shfl_xor(mx, 2));
        mx = fmaxf(mx, __shfl_xor(mx, 4));
        mx = fmaxf(mx, __shfl_xor(mx, 8));
        float mnew = fmaxf(m_i[i][rg], mx);
        float alpha = __expf(m_i[i][rg] - mnew);
        m_i[i][rg] = mnew;
        const int row = w32 + i * 16 + q * 4 + rg;
        float sum = 0.f;
#pragma unroll
        for (int j = 0; j < 8; ++j) {
          float p = __expf(sacc[i][j][rg] - mnew);
          sum += p;
          sP[row * 136 + j * 16 + fr] = (_Float16)p;
        }
        sum += __shfl_xor(sum, 1);
        sum += __shfl_xor(sum, 2);
        sum += __shfl_xor(sum, 4);
        sum += __shfl_xor(sum, 8);
        l_i[i][rg] = l_i[i][rg] * alpha + sum;
#pragma unroll
        for (int j = 0; j < 8; ++j) oacc[i][j][rg] *= alpha;
      }
    // ---- O += P @ V (plain fp16; V rows = K-tile rows, L2-resident) ----
    for (int ks = 0; ks < 4; ++ks) {
      __syncthreads();
      {
        const _Float16* src = &Qh[(size_t)(kt * 128 + ks * 32 + mB) * OUTC + d0];
        half8 v0 = *(const half8*)src;
        half8 v1 = *(const half8*)(src + 8);
#pragma unroll
        for (int e2 = 0; e2 < 8; ++e2) {
          sVT[(d0 + e2) * 32 + mB] = v0[e2];
          sVT[(d0 + 8 + e2) * 32 + mB] = v1[e2];
        }
      }
      __syncthreads();
      half8 pa[2];
#pragma unroll
      for (int i = 0; i < 2; ++i)
        pa[i] = *(const half8*)&sP[(w32 + i * 16 + fr) * 136 + ks * 32 + q * 8];
#pragma unroll
      for (int j = 0; j < 8; ++j) {
        half8 bv = *(const half8*)&sVT[(j * 16 + fr) * 32 + q * 8];
#pragma unroll
        for (int i = 0; i < 2; ++i)
          oacc[i][j] = __builtin_amdgcn_mfma_f32_16x16x32_f16(pa[i], bv, oacc[i][j], 0, 0, 0);
      }
    }
    __syncthreads();
  }
  // ---- normalize + write into padded conv input ----
#pragma unroll
  for (int i = 0; i < 2; ++i)
#pragma unroll
    for (int rg = 0; rg < 4; ++rg) {
      const float inv = 1.0f / l_i[i][rg];
      const int node = qBase + w32 + i * 16 + q * 4 + rg;
      size_t base = ((size_t)bb * 514 + 1 + node) * OUTC + h * HDIM + fr;
#pragma unroll
      for (int j = 0; j < 8; ++j)
        OP[base + j * 16] = (_Float16)(oacc[i][j][rg] * inv);
    }
}

// ---------------------------------------------------------------------------
// y = relu(bn2(conv1d(o)+conv_b)) via fp16 MFMA GEMM, XCD-swizzled.
// ---------------------------------------------------------------------------
__global__ __launch_bounds__(256) void k_conv_mfma(
    const _Float16* __restrict__ OP, const _Float16* __restrict__ WT,
    const float* __restrict__ cb, const float* __restrict__ g2,
    const float* __restrict__ b2, const float* __restrict__ m2,
    const float* __restrict__ v2, float* __restrict__ Y) {
  __shared__ _Float16 At[128 * 32];
  __shared__ _Float16 Bt[128 * 32];
  const int tid = threadIdx.x;
  const int lane = tid & 63, wave = tid >> 6;
  const int wr = (wave >> 1) * 64, wc = (wave & 1) * 64;
  const int id = blockIdx.y * 4 + blockIdx.x;
  const int jj = id >> 3;
  const int rowBase = ((id & 7) * 16 + (jj >> 2)) * 128;
  const int colBase = (jj & 3) * 128;
  const int b = rowBase >> 9;
  const int n0 = rowBase & 511;
  const int r = tid >> 2;
  const int ko = (tid & 3) * 8;
  floatx4 acc[4][4] = {};
  for (int k0 = 0; k0 < 3 * OUTC; k0 += 32) {
    const int tap = k0 >> 9;
    const int cib = k0 & 511;
    const size_t abase = ((size_t)b * 514 + n0 + tap) * OUTC + cib + ko;
    GLOBAL_TO_LDS16(&OP[abase + (size_t)r * OUTC],        &At[tid * 8]);
    GLOBAL_TO_LDS16(&OP[abase + (size_t)(r + 64) * OUTC], &At[2048 + tid * 8]);
    GLOBAL_TO_LDS16(&WT[(size_t)(colBase + r) * 1536 + k0 + ko],      &Bt[tid * 8]);
    GLOBAL_TO_LDS16(&WT[(size_t)(colBase + r + 64) * 1536 + k0 + ko], &Bt[2048 + tid * 8]);
    __syncthreads();
    const int fr = lane & 15, q = lane >> 4;
    half8 af[4], bf[4];
#pragma unroll
    for (int i = 0; i < 4; ++i)
      af[i] = *(const half8*)&At[(wr + i * 16 + fr) * 32 + q * 8];
#pragma unroll
    for (int j = 0; j < 4; ++j)
      bf[j] = *(const half8*)&Bt[(wc + j * 16 + fr) * 32 + q * 8];
#pragma unroll
    for (int i = 0; i < 4; ++i)
#pragma unroll
      for (int j = 0; j < 4; ++j)
        acc[i][j] = __builtin_amdgcn_mfma_f32_16x16x32_f16(af[i], bf[j], acc[i][j], 0, 0, 0);
    __syncthreads();
  }
  const int fr = lane & 15, q = lane >> 4;
  float sc[4], of[4];
#pragma unroll
  for (int j = 0; j < 4; ++j) {
    int c = colBase + wc + j * 16 + fr;
    float s = g2[c] * rsqrtf(v2[c] + EPSV);
    sc[j] = s;
    of[j] = (cb[c] - m2[c]) * s + b2[c];
  }
#pragma unroll
  for (int i = 0; i < 4; ++i) {
    const int R0r = rowBase + wr + i * 16 + q * 4;
#pragma unroll
    for (int rg = 0; rg < 4; ++rg) {
      float* dst = &Y[(size_t)(R0r + rg) * OUTC + colBase + wc + fr];
#pragma unroll
      for (int j = 0; j < 4; ++j)
        dst[j * 16] = fmaxf(fmaf(acc[i][j][rg], sc[j], of[j]), 0.0f);
    }
  }
}

// ---------------------------------------------------------------------------
extern "C" void kernel_launch(void* const* d_in, const int* in_sizes, int n_in,
                              void* d_out, int out_size, void* d_ws, size_t ws_size,
                              hipStream_t stream) {
  const float* x     = (const float*)d_in[0];
  const float* adj   = (const float*)d_in[1];
  const float* gc_w  = (const float*)d_in[2];
  const float* gc_b  = (const float*)d_in[3];
  const float* bn1_g = (const float*)d_in[4];
  const float* bn1_b = (const float*)d_in[5];
  const float* bn1_m = (const float*)d_in[6];
  const float* bn1_v = (const float*)d_in[7];
  const float* gat_w = (const float*)d_in[8];
  const float* conv_w= (const float*)d_in[9];
  const float* conv_b= (const float*)d_in[10];
  const float* bn2_g = (const float*)d_in[11];
  const float* bn2_b = (const float*)d_in[12];
  const float* bn2_m = (const float*)d_in[13];
  const float* bn2_v = (const float*)d_in[14];
  float* out = (float*)d_out;

  char* ws = (char*)d_ws;
  _Float16* STh = (_Float16*)(ws + 0);
  _Float16* STl = (_Float16*)(ws + 16777216);
  _Float16* HHh = (_Float16*)(ws + 0);
  _Float16* HHl = (_Float16*)(ws + 16777216);
  _Float16* Xh  = (_Float16*)(ws + 33554432);
  _Float16* Xl  = (_Float16*)(ws + 41943040);
  _Float16* Gh  = (_Float16*)(ws + 33554432);
  _Float16* Gl  = (_Float16*)(ws + 50331648);
  _Float16* OP  = (_Float16*)(ws + 67108864);
  _Float16* WT  = (_Float16*)(ws + 83951616);
  _Float16* ADJh= (_Float16*)(ws + 85524480);
  _Float16* ADJl= (_Float16*)(ws + 86048768);
  _Float16* GWh = (_Float16*)(ws + 86573056);
  _Float16* GWl = (_Float16*)(ws + 86835200);
  _Float16* GAh = (_Float16*)(ws + 87097344);
  _Float16* GAl = (_Float16*)(ws + 87621632);

  k_prep<<<5760, 256, 0, stream>>>(adj, gc_w, gat_w, conv_w,
                                   ADJh, ADJl, GWh, GWl, GAh, GAl, WT, OP);
  k_xsplit<<<4096, 256, 0, stream>>>(x, Xh, Xl);
  k_support_t<<<dim3(128, 4), 256, 0, stream>>>(GWh, GWl, Xh, Xl, STh, STl);
  k_gcn<<<dim3(4, 4, 32), 256, 0, stream>>>(ADJh, ADJl, STh, STl, gc_b,
                                            bn1_g, bn1_b, bn1_m, bn1_v, Gh, Gl);
  k_hh<<<dim3(4, 128), 256, 0, stream>>>(Gh, Gl, GAh, GAl, HHh, HHl);
  k_attn<<<512, 256, 0, stream>>>(HHh, HHl, OP);
  k_conv_mfma<<<dim3(4, 128), 256, 0, stream>>>(OP, WT, conv_b,
                                                bn2_g, bn2_b, bn2_m, bn2_v, out);
}